// Round 1
// baseline (3450.848 us; speedup 1.0000x reference)
//
#include <hip/hip_runtime.h>
#include <hip/hip_bf16.h>

#define F 128          // feature dim (F_IN == HID == 128)
#define NEG_SLOPE 0.2f

__device__ __forceinline__ float selu_f(float x) {
    const float a = 1.6732632423543772f, s = 1.0507009873554805f;
    return x > 0.0f ? s * x : s * a * (__expf(x) - 1.0f);
}

// float atomic max via int/uint bit tricks. Buffer initialized to 0xFFFFFFFF
// (NaN bits): as int it's -1 (any v>=0 wins), as uint it's UINT_MAX (any v<0
// wins via min) -> acts as -inf for this scheme.
__device__ __forceinline__ void atomicMaxFloat(float* addr, float v) {
    if (v >= 0.0f) atomicMax((int*)addr, __float_as_int(v));
    else           atomicMin((unsigned int*)addr, __float_as_uint(v));
}

// ---------------- GEMM: Y[n,128] = X[n,128] @ W[128,128] ----------------
// 64-row tile, K-chunks of 32, 256 threads, 8x4 register tile per thread.
__global__ __launch_bounds__(256) void gemm128(const float* __restrict__ X,
                                               const float* __restrict__ W,
                                               float* __restrict__ Y, int n) {
    __shared__ float Xl[64 * 32];    // 8 KB
    __shared__ float Wl[32 * 128];   // 16 KB
    const int tid = threadIdx.x;
    const int r0  = blockIdx.x * 64;
    const int c4  = (tid & 31) * 4;
    const int rg  = tid >> 5;   // 0..7
    float acc[8][4] = {};
    for (int kc = 0; kc < 128; kc += 32) {
        #pragma unroll
        for (int it = 0; it < 8; ++it) {
            int idx = tid + it * 256;
            int row = idx >> 5, kk = idx & 31;
            int gr = r0 + row;
            Xl[idx] = (gr < n) ? X[gr * 128 + kc + kk] : 0.0f;
        }
        #pragma unroll
        for (int it = 0; it < 16; ++it) {
            int idx = tid + it * 256;
            Wl[idx] = W[(kc + (idx >> 7)) * 128 + (idx & 127)];
        }
        __syncthreads();
        #pragma unroll
        for (int kk = 0; kk < 32; ++kk) {
            float4 wv = *(const float4*)&Wl[kk * 128 + c4];
            #pragma unroll
            for (int i = 0; i < 8; ++i) {
                float xv = Xl[(rg * 8 + i) * 32 + kk];
                acc[i][0] += xv * wv.x; acc[i][1] += xv * wv.y;
                acc[i][2] += xv * wv.z; acc[i][3] += xv * wv.w;
            }
        }
        __syncthreads();
    }
    #pragma unroll
    for (int i = 0; i < 8; ++i) {
        int r = r0 + rg * 8 + i;
        if (r < n) *(float4*)&Y[r * 128 + c4] = *(float4*)&acc[i][0];
    }
}

// ------------- per-node attention dots: as[i]=h_i.a_src, ad[i]=h_i.a_dst ----
__global__ __launch_bounds__(256) void alphas_kernel(const float* __restrict__ h,
                                                     const float* __restrict__ a_src,
                                                     const float* __restrict__ a_dst,
                                                     float* __restrict__ as_,
                                                     float* __restrict__ ad_, int n) {
    int w = (blockIdx.x * 256 + threadIdx.x) >> 6;
    int lane = threadIdx.x & 63;
    if (w >= n) return;
    float2 hv = *(const float2*)&h[w * 128 + lane * 2];
    float2 sv = *(const float2*)&a_src[lane * 2];
    float2 dv = *(const float2*)&a_dst[lane * 2];
    float s = hv.x * sv.x + hv.y * sv.y;
    float d = hv.x * dv.x + hv.y * dv.y;
    #pragma unroll
    for (int off = 32; off > 0; off >>= 1) {
        s += __shfl_down(s, off);
        d += __shfl_down(d, off);
    }
    if (lane == 0) { as_[w] = s; ad_[w] = d; }
}

// ------------- edge pass A: e = leaky_relu(as[src]+ad[dst]); segment max ----
__global__ __launch_bounds__(256) void edge_logits(const int* __restrict__ ei,
                                                   const float* __restrict__ as_,
                                                   const float* __restrict__ ad_,
                                                   float* __restrict__ ebuf,
                                                   float* __restrict__ mx,
                                                   int E, int n) {
    int e = blockIdx.x * 256 + threadIdx.x;
    int tot = E + n;
    if (e >= tot) return;
    int s, d;
    if (e < E) { s = ei[e]; d = ei[E + e]; } else { s = d = e - E; }
    float v = as_[s] + ad_[d];
    v = (v > 0.0f) ? v : NEG_SLOPE * v;
    ebuf[e] = v;
    atomicMaxFloat(&mx[d], v);
}

// ------------- edge pass B: ex = exp(e - m[dst]); segment sum ---------------
__global__ __launch_bounds__(256) void edge_exp(const int* __restrict__ ei,
                                                const float* __restrict__ mx,
                                                float* __restrict__ ebuf,
                                                float* __restrict__ denom,
                                                int E, int n) {
    int e = blockIdx.x * 256 + threadIdx.x;
    int tot = E + n;
    if (e >= tot) return;
    int d = (e < E) ? ei[E + e] : e - E;
    float ex = __expf(ebuf[e] - mx[d]);
    ebuf[e] = ex;
    unsafeAtomicAdd(&denom[d], ex);
}

// ------------- edge pass C: agg[dst] += (ex/denom[dst]) * h[src] ------------
__global__ __launch_bounds__(256) void edge_aggregate(const int* __restrict__ ei,
                                                      const float* __restrict__ h,
                                                      const float* __restrict__ ebuf,
                                                      const float* __restrict__ denom,
                                                      float* __restrict__ agg,
                                                      int E, int n) {
    int gw = (blockIdx.x * 256 + threadIdx.x) >> 6;
    int lane = threadIdx.x & 63;
    int tot = E + n;
    if (gw >= tot) return;
    int s, d;
    if (gw < E) { s = ei[gw]; d = ei[E + gw]; } else { s = d = gw - E; }
    float w = ebuf[gw] / denom[d];
    float2 hv = *(const float2*)&h[s * 128 + lane * 2];
    unsafeAtomicAdd(&agg[d * 128 + lane * 2 + 0], w * hv.x);
    unsafeAtomicAdd(&agg[d * 128 + lane * 2 + 1], w * hv.y);
}

// ------------- act = selu(agg + b), in place --------------------------------
__global__ __launch_bounds__(256) void bias_selu(float* __restrict__ agg,
                                                 const float* __restrict__ b,
                                                 int total) {
    int i4 = (blockIdx.x * 256 + threadIdx.x) * 4;
    if (i4 >= total) return;
    int col = i4 & 127;
    float4 v = *(float4*)&agg[i4];
    v.x = selu_f(v.x + b[col + 0]);
    v.y = selu_f(v.y + b[col + 1]);
    v.z = selu_f(v.z + b[col + 2]);
    v.w = selu_f(v.w + b[col + 3]);
    *(float4*)&agg[i4] = v;
}

// ------------- pooling: batch sorted -> per-block running sums, flush -------
#define NPB 128
__global__ __launch_bounds__(128) void pool_kernel(const float* __restrict__ act,
                                                   const int* __restrict__ batch,
                                                   float* __restrict__ sums,
                                                   float* __restrict__ cnts, int n) {
    int t = threadIdx.x;  // 0..127 (feature)
    int base = blockIdx.x * NPB;
    float acc = 0.0f, c = 0.0f;
    int curg = -1;
    for (int i = 0; i < NPB; ++i) {
        int node = base + i;
        if (node >= n) break;
        int g = batch[node];
        if (g != curg) {
            if (curg >= 0) {
                unsafeAtomicAdd(&sums[curg * 128 + t], acc);
                if (t == 0) unsafeAtomicAdd(&cnts[curg], c);
            }
            curg = g; acc = 0.0f; c = 0.0f;
        }
        acc += act[node * 128 + t];
        c += 1.0f;
    }
    if (curg >= 0) {
        unsafeAtomicAdd(&sums[curg * 128 + t], acc);
        if (t == 0) unsafeAtomicAdd(&cnts[curg], c);
    }
}

// ------------- head: selu(pool) -> fc1+selu -> fc2 -> log_softmax -----------
__global__ __launch_bounds__(128) void head_kernel(const float* __restrict__ sums,
                                                   const float* __restrict__ cnts,
                                                   const float* __restrict__ Wfc1,
                                                   const float* __restrict__ bfc1,
                                                   const float* __restrict__ Wfc2,
                                                   const float* __restrict__ bfc2,
                                                   float* __restrict__ out) {
    __shared__ float p[128];
    __shared__ float q[64];
    __shared__ float l[10];
    __shared__ float red[2];
    int g = blockIdx.x, t = threadIdx.x;
    float d = fmaxf(cnts[g], 1.0f);
    p[t] = selu_f(sums[g * 128 + t] / d);
    __syncthreads();
    if (t < 64) {
        float a = bfc1[t];
        #pragma unroll 8
        for (int k = 0; k < 128; ++k) a += p[k] * Wfc1[k * 64 + t];
        q[t] = selu_f(a);
    }
    __syncthreads();
    if (t < 10) {
        float a = bfc2[t];
        #pragma unroll
        for (int k = 0; k < 64; ++k) a += q[k] * Wfc2[k * 10 + t];
        l[t] = a;
    }
    __syncthreads();
    if (t == 0) {
        float m = l[0];
        for (int c = 1; c < 10; ++c) m = fmaxf(m, l[c]);
        float s = 0.0f;
        for (int c = 0; c < 10; ++c) s += __expf(l[c] - m);
        red[0] = m; red[1] = logf(s);
    }
    __syncthreads();
    if (t < 10) out[g * 10 + t] = l[t] - red[0] - red[1];
}

extern "C" void kernel_launch(void* const* d_in, const int* in_sizes, int n_in,
                              void* d_out, int out_size, void* d_ws, size_t ws_size,
                              hipStream_t stream) {
    const float* x      = (const float*)d_in[0];
    const int*   ei     = (const int*)d_in[1];
    const int*   batch  = (const int*)d_in[2];
    const float* W1     = (const float*)d_in[3];
    const float* asrc1  = (const float*)d_in[4];
    const float* adst1  = (const float*)d_in[5];
    const float* b1     = (const float*)d_in[6];
    const float* W2     = (const float*)d_in[7];
    const float* asrc2  = (const float*)d_in[8];
    const float* adst2  = (const float*)d_in[9];
    const float* b2     = (const float*)d_in[10];
    const float* Wfc1   = (const float*)d_in[11];
    const float* bfc1   = (const float*)d_in[12];
    const float* Wfc2   = (const float*)d_in[13];
    const float* bfc2   = (const float*)d_in[14];
    float* out = (float*)d_out;

    const int N = in_sizes[0] / 128;
    const int E = in_sizes[1] / 2;
    const int G = out_size / 10;
    const int TOT = E + N;  // edges incl. self loops

    // workspace layout (floats)
    float* bufH  = (float*)d_ws;            // N*128  (h)
    float* bufA  = bufH + (size_t)N * 128;  // N*128  (agg -> act, in place)
    float* ebuf  = bufA + (size_t)N * 128;  // E+N
    float* mx    = ebuf + TOT;              // N
    float* denom = mx + N;                  // N
    float* as_   = denom + N;               // N
    float* ad_   = as_ + N;                 // N
    float* sums  = ad_ + N;                 // G*128
    float* cnts  = sums + (size_t)G * 128;  // G

    const int gemmGrid  = (N + 63) / 64;
    const int nodeWaves = (N + 3) / 4;           // alphas: 4 waves/block
    const int edgeGrid  = (TOT + 255) / 256;
    const int aggGrid   = (TOT + 3) / 4;         // 4 edges/block (wave per edge)
    const int seluGrid  = (N * 128 / 4 + 255) / 256;
    const int poolGrid  = (N + NPB - 1) / NPB;

    // ---------------- layer 1 ----------------
    hipMemsetAsync(bufA, 0, (size_t)N * 128 * 4, stream);
    hipMemsetAsync(mx, 0xFF, (size_t)N * 4, stream);
    hipMemsetAsync(denom, 0, (size_t)N * 4, stream);
    gemm128<<<gemmGrid, 256, 0, stream>>>(x, W1, bufH, N);
    alphas_kernel<<<nodeWaves, 256, 0, stream>>>(bufH, asrc1, adst1, as_, ad_, N);
    edge_logits<<<edgeGrid, 256, 0, stream>>>(ei, as_, ad_, ebuf, mx, E, N);
    edge_exp<<<edgeGrid, 256, 0, stream>>>(ei, mx, ebuf, denom, E, N);
    edge_aggregate<<<aggGrid, 256, 0, stream>>>(ei, bufH, ebuf, denom, bufA, E, N);
    bias_selu<<<seluGrid, 256, 0, stream>>>(bufA, b1, N * 128);

    // ---------------- layer 2 ----------------
    gemm128<<<gemmGrid, 256, 0, stream>>>(bufA, W2, bufH, N);
    hipMemsetAsync(mx, 0xFF, (size_t)N * 4, stream);
    hipMemsetAsync(denom, 0, (size_t)N * 4, stream);
    alphas_kernel<<<nodeWaves, 256, 0, stream>>>(bufH, asrc2, adst2, as_, ad_, N);
    edge_logits<<<edgeGrid, 256, 0, stream>>>(ei, as_, ad_, ebuf, mx, E, N);
    edge_exp<<<edgeGrid, 256, 0, stream>>>(ei, mx, ebuf, denom, E, N);
    hipMemsetAsync(bufA, 0, (size_t)N * 128 * 4, stream);  // after gemm read it
    edge_aggregate<<<aggGrid, 256, 0, stream>>>(ei, bufH, ebuf, denom, bufA, E, N);
    bias_selu<<<seluGrid, 256, 0, stream>>>(bufA, b2, N * 128);

    // ---------------- pool + head ----------------
    hipMemsetAsync(sums, 0, (size_t)G * 128 * 4, stream);
    hipMemsetAsync(cnts, 0, (size_t)G * 4, stream);
    pool_kernel<<<poolGrid, 128, 0, stream>>>(bufA, batch, sums, cnts, N);
    head_kernel<<<G, 128, 0, stream>>>(sums, cnts, Wfc1, bfc1, Wfc2, bfc2, out);
}

// Round 2
// 817.997 us; speedup vs baseline: 4.2187x; 4.2187x over previous
//
#include <hip/hip_runtime.h>
#include <hip/hip_bf16.h>

#define NEG_SLOPE 0.2f

__device__ __forceinline__ float selu_f(float x) {
    const float a = 1.6732632423543772f, s = 1.0507009873554805f;
    return x > 0.0f ? s * x : s * a * (__expf(x) - 1.0f);
}

// ---------------- GEMM: Y[n,128] = X[n,128] @ W[128,128] ----------------
__global__ __launch_bounds__(256) void gemm128(const float* __restrict__ X,
                                               const float* __restrict__ W,
                                               float* __restrict__ Y, int n) {
    __shared__ float Xl[64 * 32];    // 8 KB
    __shared__ float Wl[32 * 128];   // 16 KB
    const int tid = threadIdx.x;
    const int r0  = blockIdx.x * 64;
    const int c4  = (tid & 31) * 4;
    const int rg  = tid >> 5;   // 0..7
    float acc[8][4] = {};
    for (int kc = 0; kc < 128; kc += 32) {
        #pragma unroll
        for (int it = 0; it < 8; ++it) {
            int idx = tid + it * 256;
            int row = idx >> 5, kk = idx & 31;
            int gr = r0 + row;
            Xl[idx] = (gr < n) ? X[gr * 128 + kc + kk] : 0.0f;
        }
        #pragma unroll
        for (int it = 0; it < 16; ++it) {
            int idx = tid + it * 256;
            Wl[idx] = W[(kc + (idx >> 7)) * 128 + (idx & 127)];
        }
        __syncthreads();
        #pragma unroll
        for (int kk = 0; kk < 32; ++kk) {
            float4 wv = *(const float4*)&Wl[kk * 128 + c4];
            #pragma unroll
            for (int i = 0; i < 8; ++i) {
                float xv = Xl[(rg * 8 + i) * 32 + kk];
                acc[i][0] += xv * wv.x; acc[i][1] += xv * wv.y;
                acc[i][2] += xv * wv.z; acc[i][3] += xv * wv.w;
            }
        }
        __syncthreads();
    }
    #pragma unroll
    for (int i = 0; i < 8; ++i) {
        int r = r0 + rg * 8 + i;
        if (r < n) *(float4*)&Y[r * 128 + c4] = *(float4*)&acc[i][0];
    }
}

// ------------- per-node attention dots ----------------------------------
__global__ __launch_bounds__(256) void alphas_kernel(const float* __restrict__ h,
                                                     const float* __restrict__ a_src,
                                                     const float* __restrict__ a_dst,
                                                     float* __restrict__ as_,
                                                     float* __restrict__ ad_, int n) {
    int w = (blockIdx.x * 256 + threadIdx.x) >> 6;
    int lane = threadIdx.x & 63;
    if (w >= n) return;
    float2 hv = *(const float2*)&h[(size_t)w * 128 + lane * 2];
    float2 sv = *(const float2*)&a_src[lane * 2];
    float2 dv = *(const float2*)&a_dst[lane * 2];
    float s = hv.x * sv.x + hv.y * sv.y;
    float d = hv.x * dv.x + hv.y * dv.y;
    #pragma unroll
    for (int off = 32; off > 0; off >>= 1) {
        s += __shfl_down(s, off);
        d += __shfl_down(d, off);
    }
    if (lane == 0) { as_[w] = s; ad_[w] = d; }
}

// ---------------- CSR build: histogram -> scan -> scatter ----------------
__global__ __launch_bounds__(256) void hist_dst(const int* __restrict__ ei,
                                                int* __restrict__ cnt, int E, int n) {
    int e = blockIdx.x * 256 + threadIdx.x;
    if (e >= E + n) return;
    int d = (e < E) ? ei[E + e] : e - E;
    atomicAdd(&cnt[d], 1);
}

// per-block exclusive scan (1024 elems / block of 256 threads)
__global__ __launch_bounds__(256) void scanA(const int* __restrict__ cnt,
                                             int* __restrict__ part,
                                             int* __restrict__ bsum, int n) {
    __shared__ int sh[256];
    int t = threadIdx.x;
    int base = blockIdx.x * 1024 + t * 4;
    int v0 = (base + 0 < n) ? cnt[base + 0] : 0;
    int v1 = (base + 1 < n) ? cnt[base + 1] : 0;
    int v2 = (base + 2 < n) ? cnt[base + 2] : 0;
    int v3 = (base + 3 < n) ? cnt[base + 3] : 0;
    int tot = v0 + v1 + v2 + v3;
    sh[t] = tot;
    __syncthreads();
    for (int off = 1; off < 256; off <<= 1) {
        int add = (t >= off) ? sh[t - off] : 0;
        __syncthreads();
        sh[t] += add;
        __syncthreads();
    }
    int ex = sh[t] - tot;
    if (t == 255) bsum[blockIdx.x] = sh[255];
    if (base + 0 < n) part[base + 0] = ex;
    if (base + 1 < n) part[base + 1] = ex + v0;
    if (base + 2 < n) part[base + 2] = ex + v0 + v1;
    if (base + 3 < n) part[base + 3] = ex + v0 + v1 + v2;
}

__global__ void scanB(int* __restrict__ bsum, int nb) {
    if (threadIdx.x == 0 && blockIdx.x == 0) {
        int run = 0;
        for (int i = 0; i < nb; ++i) { int v = bsum[i]; bsum[i] = run; run += v; }
    }
}

__global__ __launch_bounds__(256) void scanC(int* __restrict__ rowptr,
                                             const int* __restrict__ bsum,
                                             int* __restrict__ cursor, int n, int tot) {
    int i = blockIdx.x * 256 + threadIdx.x;
    if (i < n) {
        int v = rowptr[i] + bsum[i >> 10];
        rowptr[i] = v;
        cursor[i] = v;
    } else if (i == n) {
        rowptr[n] = tot;
    }
}

__global__ __launch_bounds__(256) void scatter_edges(const int* __restrict__ ei,
                                                     int* __restrict__ cursor,
                                                     int* __restrict__ col, int E, int n) {
    int e = blockIdx.x * 256 + threadIdx.x;
    if (e >= E + n) return;
    int s, d;
    if (e < E) { s = ei[e]; d = ei[E + e]; } else { s = d = e - E; }
    int pos = atomicAdd(&cursor[d], 1);
    col[pos] = s;
}

// --------- fused GAT per-dst: softmax over edges + weighted agg + selu ----
// one wave per destination node; lanes = edges in phase 1, features in phase 2
__global__ __launch_bounds__(256) void gat_csr(const int* __restrict__ rowptr,
                                               const int* __restrict__ col,
                                               const float* __restrict__ h,
                                               const float* __restrict__ as_,
                                               const float* __restrict__ ad_,
                                               const float* __restrict__ bias,
                                               float* __restrict__ out, int n) {
    int node = (blockIdx.x * 256 + threadIdx.x) >> 6;
    int lane = threadIdx.x & 63;
    if (node >= n) return;
    int beg = rowptr[node], end = rowptr[node + 1];
    float add = ad_[node];
    float m = -INFINITY, s = 0.0f;
    float accx = 0.0f, accy = 0.0f;
    for (int c = beg; c < end; c += 64) {
        int j = c + lane;
        int cntv = min(64, end - c);
        int srcn = (j < end) ? col[j] : 0;
        float v;
        if (j < end) {
            v = as_[srcn] + add;
            v = (v > 0.0f) ? v : NEG_SLOPE * v;
        } else {
            v = -INFINITY;
        }
        float cm = v;
        #pragma unroll
        for (int off = 32; off > 0; off >>= 1) cm = fmaxf(cm, __shfl_xor(cm, off));
        float nm = fmaxf(m, cm);
        float w = (j < end) ? __expf(v - nm) : 0.0f;
        float ws = w;
        #pragma unroll
        for (int off = 32; off > 0; off >>= 1) ws += __shfl_xor(ws, off);
        float scale = (m == -INFINITY) ? 0.0f : __expf(m - nm);
        s = s * scale + ws;
        accx *= scale; accy *= scale;
        for (int t = 0; t < cntv; ++t) {
            float wt = __shfl(w, t);
            int sn = __shfl(srcn, t);
            float2 hv = *(const float2*)&h[(size_t)sn * 128 + lane * 2];
            accx += wt * hv.x;
            accy += wt * hv.y;
        }
        m = nm;
    }
    float inv = 1.0f / s;
    float2 r;
    r.x = selu_f(accx * inv + bias[lane * 2 + 0]);
    r.y = selu_f(accy * inv + bias[lane * 2 + 1]);
    *(float2*)&out[(size_t)node * 128 + lane * 2] = r;
}

// ------------- pooling: batch sorted -> per-block running sums, flush -----
#define NPB 128
__global__ __launch_bounds__(128) void pool_kernel(const float* __restrict__ act,
                                                   const int* __restrict__ batch,
                                                   float* __restrict__ sums,
                                                   float* __restrict__ cnts, int n) {
    int t = threadIdx.x;
    int base = blockIdx.x * NPB;
    float acc = 0.0f, c = 0.0f;
    int curg = -1;
    for (int i = 0; i < NPB; ++i) {
        int node = base + i;
        if (node >= n) break;
        int g = batch[node];
        if (g != curg) {
            if (curg >= 0) {
                unsafeAtomicAdd(&sums[curg * 128 + t], acc);
                if (t == 0) unsafeAtomicAdd(&cnts[curg], c);
            }
            curg = g; acc = 0.0f; c = 0.0f;
        }
        acc += act[(size_t)node * 128 + t];
        c += 1.0f;
    }
    if (curg >= 0) {
        unsafeAtomicAdd(&sums[curg * 128 + t], acc);
        if (t == 0) unsafeAtomicAdd(&cnts[curg], c);
    }
}

// ------------- head: selu(pool) -> fc1+selu -> fc2 -> log_softmax ---------
__global__ __launch_bounds__(128) void head_kernel(const float* __restrict__ sums,
                                                   const float* __restrict__ cnts,
                                                   const float* __restrict__ Wfc1,
                                                   const float* __restrict__ bfc1,
                                                   const float* __restrict__ Wfc2,
                                                   const float* __restrict__ bfc2,
                                                   float* __restrict__ out) {
    __shared__ float p[128];
    __shared__ float q[64];
    __shared__ float l[10];
    __shared__ float red[2];
    int g = blockIdx.x, t = threadIdx.x;
    float d = fmaxf(cnts[g], 1.0f);
    p[t] = selu_f(sums[g * 128 + t] / d);
    __syncthreads();
    if (t < 64) {
        float a = bfc1[t];
        #pragma unroll 8
        for (int k = 0; k < 128; ++k) a += p[k] * Wfc1[k * 64 + t];
        q[t] = selu_f(a);
    }
    __syncthreads();
    if (t < 10) {
        float a = bfc2[t];
        #pragma unroll
        for (int k = 0; k < 64; ++k) a += q[k] * Wfc2[k * 10 + t];
        l[t] = a;
    }
    __syncthreads();
    if (t == 0) {
        float m = l[0];
        for (int c = 1; c < 10; ++c) m = fmaxf(m, l[c]);
        float sum = 0.0f;
        for (int c = 0; c < 10; ++c) sum += __expf(l[c] - m);
        red[0] = m; red[1] = logf(sum);
    }
    __syncthreads();
    if (t < 10) out[g * 10 + t] = l[t] - red[0] - red[1];
}

extern "C" void kernel_launch(void* const* d_in, const int* in_sizes, int n_in,
                              void* d_out, int out_size, void* d_ws, size_t ws_size,
                              hipStream_t stream) {
    const float* x      = (const float*)d_in[0];
    const int*   ei     = (const int*)d_in[1];
    const int*   batch  = (const int*)d_in[2];
    const float* W1     = (const float*)d_in[3];
    const float* asrc1  = (const float*)d_in[4];
    const float* adst1  = (const float*)d_in[5];
    const float* b1     = (const float*)d_in[6];
    const float* W2     = (const float*)d_in[7];
    const float* asrc2  = (const float*)d_in[8];
    const float* adst2  = (const float*)d_in[9];
    const float* b2     = (const float*)d_in[10];
    const float* Wfc1   = (const float*)d_in[11];
    const float* bfc1   = (const float*)d_in[12];
    const float* Wfc2   = (const float*)d_in[13];
    const float* bfc2   = (const float*)d_in[14];
    float* out = (float*)d_out;

    const int N = in_sizes[0] / 128;
    const int E = in_sizes[1] / 2;
    const int G = out_size / 10;
    const int TOT = E + N;

    // workspace layout
    float* bufH   = (float*)d_ws;             // N*128
    float* bufA   = bufH + (size_t)N * 128;   // N*128
    float* as_    = bufA + (size_t)N * 128;   // N
    float* ad_    = as_ + N;                  // N
    float* sums   = ad_ + N;                  // G*128
    float* cnts   = sums + (size_t)G * 128;   // G
    int*   rowptr = (int*)(cnts + G);         // N+1
    int*   cursor = rowptr + (N + 2);         // N   (doubles as histogram)
    int*   bsum   = cursor + N;               // ~N/1024 + 1
    int*   col    = bsum + 256;               // TOT

    const int gemmGrid  = (N + 63) / 64;
    const int nodeWaves = (N + 3) / 4;
    const int edgeGrid  = (TOT + 255) / 256;
    const int nb        = (N + 1023) / 1024;
    const int poolGrid  = (N + NPB - 1) / NPB;

    // ---------------- CSR build (shared by both layers) ----------------
    hipMemsetAsync(cursor, 0, (size_t)N * 4, stream);
    hist_dst<<<edgeGrid, 256, 0, stream>>>(ei, cursor, E, N);
    scanA<<<nb, 256, 0, stream>>>(cursor, rowptr, bsum, N);
    scanB<<<1, 64, 0, stream>>>(bsum, nb);
    scanC<<<(N + 256) / 256, 256, 0, stream>>>(rowptr, bsum, cursor, N, TOT);
    scatter_edges<<<edgeGrid, 256, 0, stream>>>(ei, cursor, col, E, N);

    // ---------------- layer 1 ----------------
    gemm128<<<gemmGrid, 256, 0, stream>>>(x, W1, bufH, N);
    alphas_kernel<<<nodeWaves, 256, 0, stream>>>(bufH, asrc1, adst1, as_, ad_, N);
    gat_csr<<<(N + 3) / 4, 256, 0, stream>>>(rowptr, col, bufH, as_, ad_, b1, bufA, N);

    // ---------------- layer 2 ----------------
    gemm128<<<gemmGrid, 256, 0, stream>>>(bufA, W2, bufH, N);
    alphas_kernel<<<nodeWaves, 256, 0, stream>>>(bufH, asrc2, adst2, as_, ad_, N);
    gat_csr<<<(N + 3) / 4, 256, 0, stream>>>(rowptr, col, bufH, as_, ad_, b2, bufA, N);

    // ---------------- pool + head ----------------
    hipMemsetAsync(sums, 0, (size_t)G * 128 * 4, stream);
    hipMemsetAsync(cnts, 0, (size_t)G * 4, stream);
    pool_kernel<<<poolGrid, 128, 0, stream>>>(bufA, batch, sums, cnts, N);
    head_kernel<<<G, 128, 0, stream>>>(sums, cnts, Wfc1, bfc1, Wfc2, bfc2, out);
}

// Round 3
// 659.127 us; speedup vs baseline: 5.2355x; 1.2410x over previous
//
#include <hip/hip_runtime.h>
#include <hip/hip_bf16.h>

#define NEG_SLOPE 0.2f
typedef unsigned int uint32;

__device__ __forceinline__ float selu_f(float x) {
    const float a = 1.6732632423543772f, s = 1.0507009873554805f;
    return x > 0.0f ? s * x : s * a * (__expf(x) - 1.0f);
}

__device__ __forceinline__ unsigned short f2bf(float x) {
    uint32 u = __float_as_uint(x);
    uint32 r = (u + 0x7fff + ((u >> 16) & 1)) >> 16;   // RNE
    return (unsigned short)r;
}
__device__ __forceinline__ float bf_lo(uint32 g) { return __uint_as_float(g << 16); }
__device__ __forceinline__ float bf_hi(uint32 g) { return __uint_as_float(g & 0xffff0000u); }

// ---- GEMM: hb[n,128](bf16) = X[n,128] @ W[128,128]; fused alpha dots ------
__global__ __launch_bounds__(256) void gemm128_fused(const float* __restrict__ X,
                                                     const float* __restrict__ W,
                                                     const float* __restrict__ a_src,
                                                     const float* __restrict__ a_dst,
                                                     uint32* __restrict__ hb,
                                                     float* __restrict__ as_,
                                                     float* __restrict__ ad_, int n) {
    __shared__ float Xl[64 * 32];    // 8 KB
    __shared__ float Wl[32 * 128];   // 16 KB
    const int tid = threadIdx.x;
    const int r0  = blockIdx.x * 64;
    const int l31 = tid & 31;
    const int c4  = l31 * 4;
    const int rg  = tid >> 5;   // 0..7
    float acc[8][4] = {};
    for (int kc = 0; kc < 128; kc += 32) {
        #pragma unroll
        for (int it = 0; it < 8; ++it) {
            int idx = tid + it * 256;
            int row = idx >> 5, kk = idx & 31;
            int gr = r0 + row;
            Xl[idx] = (gr < n) ? X[(size_t)gr * 128 + kc + kk] : 0.0f;
        }
        #pragma unroll
        for (int it = 0; it < 16; ++it) {
            int idx = tid + it * 256;
            Wl[idx] = W[(kc + (idx >> 7)) * 128 + (idx & 127)];
        }
        __syncthreads();
        #pragma unroll
        for (int kk = 0; kk < 32; ++kk) {
            float4 wv = *(const float4*)&Wl[kk * 128 + c4];
            #pragma unroll
            for (int i = 0; i < 8; ++i) {
                float xv = Xl[(rg * 8 + i) * 32 + kk];
                acc[i][0] += xv * wv.x; acc[i][1] += xv * wv.y;
                acc[i][2] += xv * wv.z; acc[i][3] += xv * wv.w;
            }
        }
        __syncthreads();
    }
    float4 asv = *(const float4*)&a_src[c4];
    float4 adv = *(const float4*)&a_dst[c4];
    #pragma unroll
    for (int i = 0; i < 8; ++i) {
        int r = r0 + rg * 8 + i;
        if (r >= n) continue;
        // attention dots (fp32, full precision)
        float s = acc[i][0] * asv.x + acc[i][1] * asv.y + acc[i][2] * asv.z + acc[i][3] * asv.w;
        float d = acc[i][0] * adv.x + acc[i][1] * adv.y + acc[i][2] * adv.z + acc[i][3] * adv.w;
        #pragma unroll
        for (int off = 16; off > 0; off >>= 1) {
            s += __shfl_xor(s, off);
            d += __shfl_xor(d, off);
        }
        if (l31 == 0) { as_[r] = s; ad_[r] = d; }
        uint32 lo = (uint32)f2bf(acc[i][0]) | ((uint32)f2bf(acc[i][1]) << 16);
        uint32 hi = (uint32)f2bf(acc[i][2]) | ((uint32)f2bf(acc[i][3]) << 16);
        *(uint2*)&hb[(size_t)r * 64 + l31 * 2] = make_uint2(lo, hi);
    }
}

// ---------------- CSR build: histogram -> scan -> scatter ----------------
__global__ __launch_bounds__(256) void hist_dst(const int* __restrict__ ei,
                                                int* __restrict__ cnt, int E, int n) {
    int e = blockIdx.x * 256 + threadIdx.x;
    if (e >= E + n) return;
    int d = (e < E) ? ei[E + e] : e - E;
    atomicAdd(&cnt[d], 1);
}

__global__ __launch_bounds__(256) void scanA(const int* __restrict__ cnt,
                                             int* __restrict__ part,
                                             int* __restrict__ bsum, int n) {
    __shared__ int sh[256];
    int t = threadIdx.x;
    int base = blockIdx.x * 1024 + t * 4;
    int v0 = (base + 0 < n) ? cnt[base + 0] : 0;
    int v1 = (base + 1 < n) ? cnt[base + 1] : 0;
    int v2 = (base + 2 < n) ? cnt[base + 2] : 0;
    int v3 = (base + 3 < n) ? cnt[base + 3] : 0;
    int tot = v0 + v1 + v2 + v3;
    sh[t] = tot;
    __syncthreads();
    for (int off = 1; off < 256; off <<= 1) {
        int add = (t >= off) ? sh[t - off] : 0;
        __syncthreads();
        sh[t] += add;
        __syncthreads();
    }
    int ex = sh[t] - tot;
    if (t == 255) bsum[blockIdx.x] = sh[255];
    if (base + 0 < n) part[base + 0] = ex;
    if (base + 1 < n) part[base + 1] = ex + v0;
    if (base + 2 < n) part[base + 2] = ex + v0 + v1;
    if (base + 3 < n) part[base + 3] = ex + v0 + v1 + v2;
}

// parallel exclusive scan of block sums (nb <= 256)
__global__ __launch_bounds__(256) void scanB(int* __restrict__ bsum, int nb) {
    __shared__ int sh[256];
    int t = threadIdx.x;
    int v = (t < nb) ? bsum[t] : 0;
    sh[t] = v;
    __syncthreads();
    for (int off = 1; off < 256; off <<= 1) {
        int add = (t >= off) ? sh[t - off] : 0;
        __syncthreads();
        sh[t] += add;
        __syncthreads();
    }
    if (t < nb) bsum[t] = sh[t] - v;
}

__global__ __launch_bounds__(256) void scanC(int* __restrict__ rowptr,
                                             const int* __restrict__ bsum,
                                             int* __restrict__ cursor, int n, int tot) {
    int i = blockIdx.x * 256 + threadIdx.x;
    if (i < n) {
        int v = rowptr[i] + bsum[i >> 10];
        rowptr[i] = v;
        cursor[i] = v;
    } else if (i == n) {
        rowptr[n] = tot;
    }
}

__global__ __launch_bounds__(256) void scatter_edges(const int* __restrict__ ei,
                                                     int* __restrict__ cursor,
                                                     int* __restrict__ col, int E, int n) {
    int e = blockIdx.x * 256 + threadIdx.x;
    if (e >= E + n) return;
    int s, d;
    if (e < E) { s = ei[e]; d = ei[E + e]; } else { s = d = e - E; }
    int pos = atomicAdd(&cursor[d], 1);
    col[pos] = s;
}

// --------- fused GAT per-dst: softmax + bf16 gather agg + bias + selu ------
__global__ __launch_bounds__(256) void gat_csr2(const int* __restrict__ rowptr,
                                                const int* __restrict__ col,
                                                const uint32* __restrict__ hb,
                                                const float* __restrict__ as_,
                                                const float* __restrict__ ad_,
                                                const float* __restrict__ bias,
                                                float* __restrict__ outb, int n) {
    __shared__ float wsh[4][64];
    __shared__ int   ssh[4][64];
    int wid  = threadIdx.x >> 6;
    int lane = threadIdx.x & 63;
    int node = blockIdx.x * 4 + wid;
    if (node >= n) return;
    int beg = rowptr[node], end = rowptr[node + 1];
    float add = ad_[node];
    float m = -INFINITY, s = 0.0f, accx = 0.0f, accy = 0.0f;
    for (int c = beg; c < end; c += 64) {
        int j = c + lane;
        int cntv = min(64, end - c);
        int srcn = (j < end) ? col[j] : 0;
        float v = (j < end) ? (as_[srcn] + add) : -INFINITY;
        v = (v > 0.0f) ? v : NEG_SLOPE * v;
        float cm = v;
        #pragma unroll
        for (int off = 32; off > 0; off >>= 1) cm = fmaxf(cm, __shfl_xor(cm, off));
        float nm = fmaxf(m, cm);
        float w = (j < end) ? __expf(v - nm) : 0.0f;
        float ws = w;
        #pragma unroll
        for (int off = 32; off > 0; off >>= 1) ws += __shfl_xor(ws, off);
        float scale = (m == -INFINITY) ? 0.0f : __expf(m - nm);
        s = s * scale + ws;
        accx *= scale; accy *= scale;
        wsh[wid][lane] = w;
        ssh[wid][lane] = srcn;  // same-wave LDS write->read: DS ops in order
        int t = 0;
        for (; t + 4 <= cntv; t += 4) {
            int s0 = ssh[wid][t + 0], s1 = ssh[wid][t + 1];
            int s2 = ssh[wid][t + 2], s3 = ssh[wid][t + 3];
            float w0 = wsh[wid][t + 0], w1 = wsh[wid][t + 1];
            float w2 = wsh[wid][t + 2], w3 = wsh[wid][t + 3];
            uint32 g0 = hb[(size_t)s0 * 64 + lane];
            uint32 g1 = hb[(size_t)s1 * 64 + lane];
            uint32 g2 = hb[(size_t)s2 * 64 + lane];
            uint32 g3 = hb[(size_t)s3 * 64 + lane];
            accx += w0 * bf_lo(g0) + w1 * bf_lo(g1) + w2 * bf_lo(g2) + w3 * bf_lo(g3);
            accy += w0 * bf_hi(g0) + w1 * bf_hi(g1) + w2 * bf_hi(g2) + w3 * bf_hi(g3);
        }
        for (; t < cntv; ++t) {
            int sn = ssh[wid][t];
            float wt = wsh[wid][t];
            uint32 g = hb[(size_t)sn * 64 + lane];
            accx += wt * bf_lo(g);
            accy += wt * bf_hi(g);
        }
        m = nm;
    }
    float inv = 1.0f / s;
    float2 r;
    r.x = selu_f(accx * inv + bias[lane * 2 + 0]);
    r.y = selu_f(accy * inv + bias[lane * 2 + 1]);
    *(float2*)&outb[(size_t)node * 128 + lane * 2] = r;
}

// ------------- pooling: batch sorted -> per-block running sums, flush -----
#define NPB 128
__global__ __launch_bounds__(128) void pool_kernel(const float* __restrict__ act,
                                                   const int* __restrict__ batch,
                                                   float* __restrict__ sums,
                                                   float* __restrict__ cnts, int n) {
    int t = threadIdx.x;
    int base = blockIdx.x * NPB;
    float acc = 0.0f, c = 0.0f;
    int curg = -1;
    for (int i = 0; i < NPB; ++i) {
        int node = base + i;
        if (node >= n) break;
        int g = batch[node];
        if (g != curg) {
            if (curg >= 0) {
                unsafeAtomicAdd(&sums[curg * 128 + t], acc);
                if (t == 0) unsafeAtomicAdd(&cnts[curg], c);
            }
            curg = g; acc = 0.0f; c = 0.0f;
        }
        acc += act[(size_t)node * 128 + t];
        c += 1.0f;
    }
    if (curg >= 0) {
        unsafeAtomicAdd(&sums[curg * 128 + t], acc);
        if (t == 0) unsafeAtomicAdd(&cnts[curg], c);
    }
}

// ------------- head: selu(pool) -> fc1+selu -> fc2 -> log_softmax ---------
__global__ __launch_bounds__(128) void head_kernel(const float* __restrict__ sums,
                                                   const float* __restrict__ cnts,
                                                   const float* __restrict__ Wfc1,
                                                   const float* __restrict__ bfc1,
                                                   const float* __restrict__ Wfc2,
                                                   const float* __restrict__ bfc2,
                                                   float* __restrict__ out) {
    __shared__ float p[128];
    __shared__ float q[64];
    __shared__ float l[10];
    __shared__ float red[2];
    int g = blockIdx.x, t = threadIdx.x;
    float d = fmaxf(cnts[g], 1.0f);
    p[t] = selu_f(sums[g * 128 + t] / d);
    __syncthreads();
    if (t < 64) {
        float a = bfc1[t];
        #pragma unroll 8
        for (int k = 0; k < 128; ++k) a += p[k] * Wfc1[k * 64 + t];
        q[t] = selu_f(a);
    }
    __syncthreads();
    if (t < 10) {
        float a = bfc2[t];
        #pragma unroll
        for (int k = 0; k < 64; ++k) a += q[k] * Wfc2[k * 10 + t];
        l[t] = a;
    }
    __syncthreads();
    if (t == 0) {
        float m = l[0];
        for (int c = 1; c < 10; ++c) m = fmaxf(m, l[c]);
        float sum = 0.0f;
        for (int c = 0; c < 10; ++c) sum += __expf(l[c] - m);
        red[0] = m; red[1] = logf(sum);
    }
    __syncthreads();
    if (t < 10) out[g * 10 + t] = l[t] - red[0] - red[1];
}

extern "C" void kernel_launch(void* const* d_in, const int* in_sizes, int n_in,
                              void* d_out, int out_size, void* d_ws, size_t ws_size,
                              hipStream_t stream) {
    const float* x      = (const float*)d_in[0];
    const int*   ei     = (const int*)d_in[1];
    const int*   batch  = (const int*)d_in[2];
    const float* W1     = (const float*)d_in[3];
    const float* asrc1  = (const float*)d_in[4];
    const float* adst1  = (const float*)d_in[5];
    const float* b1     = (const float*)d_in[6];
    const float* W2     = (const float*)d_in[7];
    const float* asrc2  = (const float*)d_in[8];
    const float* adst2  = (const float*)d_in[9];
    const float* b2     = (const float*)d_in[10];
    const float* Wfc1   = (const float*)d_in[11];
    const float* bfc1   = (const float*)d_in[12];
    const float* Wfc2   = (const float*)d_in[13];
    const float* bfc2   = (const float*)d_in[14];
    float* out = (float*)d_out;

    const int N = in_sizes[0] / 128;
    const int E = in_sizes[1] / 2;
    const int G = out_size / 10;
    const int TOT = E + N;

    // workspace layout
    uint32* hb    = (uint32*)d_ws;            // N*64 uints (bf16 h)
    float* bufA   = (float*)(hb + (size_t)N * 64); // N*128 fp32
    float* as_    = bufA + (size_t)N * 128;   // N
    float* ad_    = as_ + N;                  // N
    float* sums   = ad_ + N;                  // G*128
    float* cnts   = sums + (size_t)G * 128;   // G
    int*   rowptr = (int*)(cnts + G);         // N+1
    int*   cursor = rowptr + (N + 2);         // N (doubles as histogram)
    int*   bsum   = cursor + N;               // <=256
    int*   col    = bsum + 256;               // TOT

    const int gemmGrid = (N + 63) / 64;
    const int edgeGrid = (TOT + 255) / 256;
    const int nb       = (N + 1023) / 1024;
    const int poolGrid = (N + NPB - 1) / NPB;

    // ---------------- CSR build (shared by both layers) ----------------
    hipMemsetAsync(cursor, 0, (size_t)N * 4, stream);
    hist_dst<<<edgeGrid, 256, 0, stream>>>(ei, cursor, E, N);
    scanA<<<nb, 256, 0, stream>>>(cursor, rowptr, bsum, N);
    scanB<<<1, 256, 0, stream>>>(bsum, nb);
    scanC<<<(N + 256) / 256, 256, 0, stream>>>(rowptr, bsum, cursor, N, TOT);
    scatter_edges<<<edgeGrid, 256, 0, stream>>>(ei, cursor, col, E, N);

    // ---------------- layer 1 ----------------
    gemm128_fused<<<gemmGrid, 256, 0, stream>>>(x, W1, asrc1, adst1, hb, as_, ad_, N);
    gat_csr2<<<(N + 3) / 4, 256, 0, stream>>>(rowptr, col, hb, as_, ad_, b1, bufA, N);

    // ---------------- layer 2 ----------------
    gemm128_fused<<<gemmGrid, 256, 0, stream>>>(bufA, W2, asrc2, adst2, hb, as_, ad_, N);
    gat_csr2<<<(N + 3) / 4, 256, 0, stream>>>(rowptr, col, hb, as_, ad_, b2, bufA, N);

    // ---------------- pool + head ----------------
    hipMemsetAsync(sums, 0, (size_t)G * 128 * 4, stream);
    hipMemsetAsync(cnts, 0, (size_t)G * 4, stream);
    pool_kernel<<<poolGrid, 128, 0, stream>>>(bufA, batch, sums, cnts, N);
    head_kernel<<<G, 128, 0, stream>>>(sums, cnts, Wfc1, bfc1, Wfc2, bfc2, out);
}

// Round 4
// 539.279 us; speedup vs baseline: 6.3990x; 1.2222x over previous
//
#include <hip/hip_runtime.h>
#include <hip/hip_bf16.h>

#define NEG_SLOPE 0.2f
typedef unsigned int uint32;

#define BSHIFT 9
#define BSIZE 512          // nodes per bucket
#define MAXB 256           // max buckets (N < 131072)
#define PCHUNK 4096        // edges per partition block

__device__ __forceinline__ float selu_f(float x) {
    const float a = 1.6732632423543772f, s = 1.0507009873554805f;
    return x > 0.0f ? s * x : s * a * (__expf(x) - 1.0f);
}

__device__ __forceinline__ unsigned short f2bf(float x) {
    uint32 u = __float_as_uint(x);
    uint32 r = (u + 0x7fff + ((u >> 16) & 1)) >> 16;   // RNE
    return (unsigned short)r;
}
__device__ __forceinline__ float bf_lo(uint32 g) { return __uint_as_float(g << 16); }
__device__ __forceinline__ float bf_hi(uint32 g) { return __uint_as_float(g & 0xffff0000u); }

// ---- GEMM: hb[n,128](bf16) = X[n,128] @ W[128,128]; fused alpha dots ------
__global__ __launch_bounds__(256) void gemm128_fused(const float* __restrict__ X,
                                                     const float* __restrict__ W,
                                                     const float* __restrict__ a_src,
                                                     const float* __restrict__ a_dst,
                                                     uint32* __restrict__ hb,
                                                     float* __restrict__ as_,
                                                     float* __restrict__ ad_, int n) {
    __shared__ float Xl[64 * 32];
    __shared__ float Wl[32 * 128];
    const int tid = threadIdx.x;
    const int r0  = blockIdx.x * 64;
    const int l31 = tid & 31;
    const int c4  = l31 * 4;
    const int rg  = tid >> 5;
    float acc[8][4] = {};
    for (int kc = 0; kc < 128; kc += 32) {
        #pragma unroll
        for (int it = 0; it < 8; ++it) {
            int idx = tid + it * 256;
            int row = idx >> 5, kk = idx & 31;
            int gr = r0 + row;
            Xl[idx] = (gr < n) ? X[(size_t)gr * 128 + kc + kk] : 0.0f;
        }
        #pragma unroll
        for (int it = 0; it < 16; ++it) {
            int idx = tid + it * 256;
            Wl[idx] = W[(kc + (idx >> 7)) * 128 + (idx & 127)];
        }
        __syncthreads();
        #pragma unroll
        for (int kk = 0; kk < 32; ++kk) {
            float4 wv = *(const float4*)&Wl[kk * 128 + c4];
            #pragma unroll
            for (int i = 0; i < 8; ++i) {
                float xv = Xl[(rg * 8 + i) * 32 + kk];
                acc[i][0] += xv * wv.x; acc[i][1] += xv * wv.y;
                acc[i][2] += xv * wv.z; acc[i][3] += xv * wv.w;
            }
        }
        __syncthreads();
    }
    float4 asv = *(const float4*)&a_src[c4];
    float4 adv = *(const float4*)&a_dst[c4];
    #pragma unroll
    for (int i = 0; i < 8; ++i) {
        int r = r0 + rg * 8 + i;
        if (r >= n) continue;
        float s = acc[i][0] * asv.x + acc[i][1] * asv.y + acc[i][2] * asv.z + acc[i][3] * asv.w;
        float d = acc[i][0] * adv.x + acc[i][1] * adv.y + acc[i][2] * adv.z + acc[i][3] * adv.w;
        #pragma unroll
        for (int off = 16; off > 0; off >>= 1) {
            s += __shfl_xor(s, off);
            d += __shfl_xor(d, off);
        }
        if (l31 == 0) { as_[r] = s; ad_[r] = d; }
        uint32 lo = (uint32)f2bf(acc[i][0]) | ((uint32)f2bf(acc[i][1]) << 16);
        uint32 hi = (uint32)f2bf(acc[i][2]) | ((uint32)f2bf(acc[i][3]) << 16);
        *(uint2*)&hb[(size_t)r * 64 + l31 * 2] = make_uint2(lo, hi);
    }
}

// ------------- bucket histogram over dst>>BSHIFT (LDS, then merge) --------
__global__ __launch_bounds__(256) void bucket_hist(const int* __restrict__ ei,
                                                   int* __restrict__ gcnt, int E, int TOT) {
    __shared__ int lh[MAXB];
    int t = threadIdx.x;
    lh[t] = 0;
    __syncthreads();
    int eb = blockIdx.x * PCHUNK;
    #pragma unroll
    for (int k = 0; k < PCHUNK / 256; ++k) {
        int e = eb + k * 256 + t;
        if (e < TOT) {
            int d = (e < E) ? ei[E + e] : e - E;
            atomicAdd(&lh[d >> BSHIFT], 1);
        }
    }
    __syncthreads();
    if (lh[t] > 0) atomicAdd(&gcnt[t], lh[t]);
}

// ------------- exclusive scan of bucket counts (single block) -------------
__global__ __launch_bounds__(256) void bucket_scan(const int* __restrict__ gcnt,
                                                   int* __restrict__ bstart,
                                                   int* __restrict__ gcursor, int NB, int TOT) {
    __shared__ int sh[256];
    int t = threadIdx.x;
    int v = (t < NB) ? gcnt[t] : 0;
    sh[t] = v;
    __syncthreads();
    for (int off = 1; off < 256; off <<= 1) {
        int add = (t >= off) ? sh[t - off] : 0;
        __syncthreads();
        sh[t] += add;
        __syncthreads();
    }
    int ex = sh[t] - v;
    if (t < NB) { bstart[t] = ex; gcursor[t] = ex; }
    if (t == 0) bstart[NB] = TOT;
}

// ------------- partition edges into buckets (LDS counting sort) -----------
// tmp[pos] packs (dst & 511) << 17 | src   (src < 2^17)
__global__ __launch_bounds__(256) void partition_edges(const int* __restrict__ ei,
                                                       int* __restrict__ gcursor,
                                                       uint32* __restrict__ tmp,
                                                       int E, int TOT) {
    __shared__ int lcnt[MAXB];
    __shared__ int lstart[MAXB];
    __shared__ int lcur[MAXB];
    __shared__ int gbase[MAXB];
    __shared__ uint32 staged[PCHUNK];
    __shared__ unsigned char bslot[PCHUNK];
    int t = threadIdx.x;
    int eb = blockIdx.x * PCHUNK;
    int sreg[16], dreg[16];
    #pragma unroll
    for (int k = 0; k < 16; ++k) {
        int e = eb + k * 256 + t;
        if (e < TOT) {
            if (e < E) { sreg[k] = ei[e]; dreg[k] = ei[E + e]; }
            else       { sreg[k] = dreg[k] = e - E; }
        } else dreg[k] = -1;
    }
    lcnt[t] = 0;
    __syncthreads();
    #pragma unroll
    for (int k = 0; k < 16; ++k)
        if (dreg[k] >= 0) atomicAdd(&lcnt[dreg[k] >> BSHIFT], 1);
    __syncthreads();
    int v = lcnt[t];
    lstart[t] = v;
    __syncthreads();
    for (int off = 1; off < 256; off <<= 1) {
        int add = (t >= off) ? lstart[t - off] : 0;
        __syncthreads();
        lstart[t] += add;
        __syncthreads();
    }
    int ex = lstart[t] - v;
    __syncthreads();
    lstart[t] = ex;
    lcur[t] = ex;
    if (v > 0) gbase[t] = atomicAdd(&gcursor[t], v);
    __syncthreads();
    #pragma unroll
    for (int k = 0; k < 16; ++k) {
        int d = dreg[k];
        if (d >= 0) {
            int b = d >> BSHIFT;
            int p = atomicAdd(&lcur[b], 1);
            staged[p] = ((uint32)(d & (BSIZE - 1)) << 17) | (uint32)sreg[k];
            bslot[p] = (unsigned char)b;
        }
    }
    __syncthreads();
    int nvalid = TOT - eb; if (nvalid > PCHUNK) nvalid = PCHUNK;
    for (int i = t; i < nvalid; i += 256) {
        int b = bslot[i];
        tmp[gbase[b] + (i - lstart[b])] = staged[i];
    }
}

// ------------- per-bucket: per-node scan -> rowptr + col scatter ----------
__global__ __launch_bounds__(256) void bucket_build(const uint32* __restrict__ tmp,
                                                    const int* __restrict__ bstart,
                                                    int* __restrict__ rowptr,
                                                    int* __restrict__ col,
                                                    int N, int TOT, int NB) {
    __shared__ int cnt[BSIZE];
    __shared__ int sums[256];
    int b = blockIdx.x, t = threadIdx.x;
    int lo = b << BSHIFT;
    int nn = N - lo; if (nn > BSIZE) nn = BSIZE;
    cnt[t] = 0; cnt[t + 256] = 0;
    __syncthreads();
    int ebeg = bstart[b], eend = bstart[b + 1];
    for (int i = ebeg + t; i < eend; i += 256)
        atomicAdd(&cnt[tmp[i] >> 17], 1);
    __syncthreads();
    int c0 = cnt[2 * t], c1 = cnt[2 * t + 1];
    int s2 = c0 + c1;
    sums[t] = s2;
    __syncthreads();
    for (int off = 1; off < 256; off <<= 1) {
        int add = (t >= off) ? sums[t - off] : 0;
        __syncthreads();
        sums[t] += add;
        __syncthreads();
    }
    int ex = sums[t] - s2;
    int st0 = ebeg + ex, st1 = st0 + c0;
    if (2 * t < nn)     rowptr[lo + 2 * t] = st0;
    if (2 * t + 1 < nn) rowptr[lo + 2 * t + 1] = st1;
    cnt[2 * t] = st0; cnt[2 * t + 1] = st1;
    __syncthreads();
    for (int i = ebeg + t; i < eend; i += 256) {
        uint32 u = tmp[i];
        int p = atomicAdd(&cnt[u >> 17], 1);
        col[p] = (int)(u & 0x1FFFFu);
    }
    if (b == NB - 1 && t == 0) rowptr[N] = TOT;
}

// --------- fused GAT per-dst: softmax + bf16 gather agg + bias + selu ------
__global__ __launch_bounds__(256) void gat_csr2(const int* __restrict__ rowptr,
                                                const int* __restrict__ col,
                                                const uint32* __restrict__ hb,
                                                const float* __restrict__ as_,
                                                const float* __restrict__ ad_,
                                                const float* __restrict__ bias,
                                                float* __restrict__ outb, int n) {
    __shared__ float wsh[4][64];
    __shared__ int   ssh[4][64];
    int wid  = threadIdx.x >> 6;
    int lane = threadIdx.x & 63;
    int node = blockIdx.x * 4 + wid;
    if (node >= n) return;
    int beg = rowptr[node], end = rowptr[node + 1];
    float add = ad_[node];
    float m = -INFINITY, s = 0.0f, accx = 0.0f, accy = 0.0f;
    for (int c = beg; c < end; c += 64) {
        int j = c + lane;
        int cntv = min(64, end - c);
        int srcn = (j < end) ? col[j] : 0;
        float v = (j < end) ? (as_[srcn] + add) : -INFINITY;
        v = (v > 0.0f) ? v : NEG_SLOPE * v;
        float cm = v;
        #pragma unroll
        for (int off = 32; off > 0; off >>= 1) cm = fmaxf(cm, __shfl_xor(cm, off));
        float nm = fmaxf(m, cm);
        float w = (j < end) ? __expf(v - nm) : 0.0f;
        float ws = w;
        #pragma unroll
        for (int off = 32; off > 0; off >>= 1) ws += __shfl_xor(ws, off);
        float scale = (m == -INFINITY) ? 0.0f : __expf(m - nm);
        s = s * scale + ws;
        accx *= scale; accy *= scale;
        wsh[wid][lane] = w;
        ssh[wid][lane] = srcn;
        int t = 0;
        for (; t + 8 <= cntv; t += 8) {
            int   sr[8]; float wr[8]; uint32 g[8];
            #pragma unroll
            for (int q = 0; q < 8; ++q) { sr[q] = ssh[wid][t + q]; wr[q] = wsh[wid][t + q]; }
            #pragma unroll
            for (int q = 0; q < 8; ++q) g[q] = hb[(size_t)sr[q] * 64 + lane];
            #pragma unroll
            for (int q = 0; q < 8; ++q) {
                accx += wr[q] * bf_lo(g[q]);
                accy += wr[q] * bf_hi(g[q]);
            }
        }
        for (; t < cntv; ++t) {
            int sn = ssh[wid][t];
            float wt = wsh[wid][t];
            uint32 g = hb[(size_t)sn * 64 + lane];
            accx += wt * bf_lo(g);
            accy += wt * bf_hi(g);
        }
        m = nm;
    }
    float inv = 1.0f / s;
    float2 r;
    r.x = selu_f(accx * inv + bias[lane * 2 + 0]);
    r.y = selu_f(accy * inv + bias[lane * 2 + 1]);
    *(float2*)&outb[(size_t)node * 128 + lane * 2] = r;
}

// ------------- pooling: batch sorted -> per-block running sums, flush -----
#define NPB 128
__global__ __launch_bounds__(128) void pool_kernel(const float* __restrict__ act,
                                                   const int* __restrict__ batch,
                                                   float* __restrict__ sums,
                                                   float* __restrict__ cnts, int n) {
    int t = threadIdx.x;
    int base = blockIdx.x * NPB;
    float acc = 0.0f, c = 0.0f;
    int curg = -1;
    for (int i = 0; i < NPB; ++i) {
        int node = base + i;
        if (node >= n) break;
        int g = batch[node];
        if (g != curg) {
            if (curg >= 0) {
                unsafeAtomicAdd(&sums[curg * 128 + t], acc);
                if (t == 0) unsafeAtomicAdd(&cnts[curg], c);
            }
            curg = g; acc = 0.0f; c = 0.0f;
        }
        acc += act[(size_t)node * 128 + t];
        c += 1.0f;
    }
    if (curg >= 0) {
        unsafeAtomicAdd(&sums[curg * 128 + t], acc);
        if (t == 0) unsafeAtomicAdd(&cnts[curg], c);
    }
}

// ------------- head: selu(pool) -> fc1+selu -> fc2 -> log_softmax ---------
__global__ __launch_bounds__(128) void head_kernel(const float* __restrict__ sums,
                                                   const float* __restrict__ cnts,
                                                   const float* __restrict__ Wfc1,
                                                   const float* __restrict__ bfc1,
                                                   const float* __restrict__ Wfc2,
                                                   const float* __restrict__ bfc2,
                                                   float* __restrict__ out) {
    __shared__ float p[128];
    __shared__ float q[64];
    __shared__ float l[10];
    __shared__ float red[2];
    int g = blockIdx.x, t = threadIdx.x;
    float d = fmaxf(cnts[g], 1.0f);
    p[t] = selu_f(sums[g * 128 + t] / d);
    __syncthreads();
    if (t < 64) {
        float a = bfc1[t];
        #pragma unroll 8
        for (int k = 0; k < 128; ++k) a += p[k] * Wfc1[k * 64 + t];
        q[t] = selu_f(a);
    }
    __syncthreads();
    if (t < 10) {
        float a = bfc2[t];
        #pragma unroll
        for (int k = 0; k < 64; ++k) a += q[k] * Wfc2[k * 10 + t];
        l[t] = a;
    }
    __syncthreads();
    if (t == 0) {
        float m = l[0];
        for (int c = 1; c < 10; ++c) m = fmaxf(m, l[c]);
        float sum = 0.0f;
        for (int c = 0; c < 10; ++c) sum += __expf(l[c] - m);
        red[0] = m; red[1] = logf(sum);
    }
    __syncthreads();
    if (t < 10) out[g * 10 + t] = l[t] - red[0] - red[1];
}

extern "C" void kernel_launch(void* const* d_in, const int* in_sizes, int n_in,
                              void* d_out, int out_size, void* d_ws, size_t ws_size,
                              hipStream_t stream) {
    const float* x      = (const float*)d_in[0];
    const int*   ei     = (const int*)d_in[1];
    const int*   batch  = (const int*)d_in[2];
    const float* W1     = (const float*)d_in[3];
    const float* asrc1  = (const float*)d_in[4];
    const float* adst1  = (const float*)d_in[5];
    const float* b1     = (const float*)d_in[6];
    const float* W2     = (const float*)d_in[7];
    const float* asrc2  = (const float*)d_in[8];
    const float* adst2  = (const float*)d_in[9];
    const float* b2     = (const float*)d_in[10];
    const float* Wfc1   = (const float*)d_in[11];
    const float* bfc1   = (const float*)d_in[12];
    const float* Wfc2   = (const float*)d_in[13];
    const float* bfc2   = (const float*)d_in[14];
    float* out = (float*)d_out;

    const int N = in_sizes[0] / 128;
    const int E = in_sizes[1] / 2;
    const int G = out_size / 10;
    const int TOT = E + N;
    const int NB = ((N - 1) >> BSHIFT) + 1;

    // workspace layout
    uint32* hb    = (uint32*)d_ws;                   // N*64  (bf16 h)
    uint32* tmp   = hb + (size_t)N * 64;             // TOT   (packed bucket-partitioned edges)
    float* bufA   = (float*)(tmp + TOT);             // N*128 fp32
    float* as_    = bufA + (size_t)N * 128;          // N
    float* ad_    = as_ + N;                         // N
    float* sums   = ad_ + N;                         // G*128
    float* cnts   = sums + (size_t)G * 128;          // G
    int*   rowptr = (int*)(cnts + G);                // N+1
    int*   gcnt   = rowptr + (N + 2);                // 256
    int*   bstart = gcnt + MAXB;                     // 257
    int*   gcursor= bstart + MAXB + 1;               // 256
    int*   col    = gcursor + MAXB;                  // TOT

    const int gemmGrid = (N + 63) / 64;
    const int partGrid = (TOT + PCHUNK - 1) / PCHUNK;
    const int poolGrid = (N + NPB - 1) / NPB;

    // ---------------- CSR build (shared by both layers) ----------------
    hipMemsetAsync(gcnt, 0, MAXB * 4, stream);
    bucket_hist<<<partGrid, 256, 0, stream>>>(ei, gcnt, E, TOT);
    bucket_scan<<<1, 256, 0, stream>>>(gcnt, bstart, gcursor, NB, TOT);
    partition_edges<<<partGrid, 256, 0, stream>>>(ei, gcursor, tmp, E, TOT);
    bucket_build<<<NB, 256, 0, stream>>>(tmp, bstart, rowptr, col, N, TOT, NB);

    // ---------------- layer 1 ----------------
    gemm128_fused<<<gemmGrid, 256, 0, stream>>>(x, W1, asrc1, adst1, hb, as_, ad_, N);
    gat_csr2<<<(N + 3) / 4, 256, 0, stream>>>(rowptr, col, hb, as_, ad_, b1, bufA, N);

    // ---------------- layer 2 ----------------
    gemm128_fused<<<gemmGrid, 256, 0, stream>>>(bufA, W2, asrc2, adst2, hb, as_, ad_, N);
    gat_csr2<<<(N + 3) / 4, 256, 0, stream>>>(rowptr, col, hb, as_, ad_, b2, bufA, N);

    // ---------------- pool + head ----------------
    hipMemsetAsync(sums, 0, (size_t)G * 128 * 4, stream);
    hipMemsetAsync(cnts, 0, (size_t)G * 4, stream);
    pool_kernel<<<poolGrid, 128, 0, stream>>>(bufA, batch, sums, cnts, N);
    head_kernel<<<G, 128, 0, stream>>>(sums, cnts, Wfc1, bfc1, Wfc2, bfc2, out);
}

// Round 5
// 463.473 us; speedup vs baseline: 7.4456x; 1.1636x over previous
//
#include <hip/hip_runtime.h>
#include <hip/hip_bf16.h>

#define NEG_SLOPE 0.2f
typedef unsigned int uint32;
typedef unsigned short ushort16;

#define BSHIFT 9
#define BSIZE 512          // nodes per bucket
#define MAXB 256           // max buckets (N < 131072)
#define PCHUNK 4096        // edges per partition block

typedef __attribute__((ext_vector_type(8))) __bf16 bf16x8;
typedef __attribute__((ext_vector_type(4))) float f32x4;

__device__ __forceinline__ float selu_f(float x) {
    const float a = 1.6732632423543772f, s = 1.0507009873554805f;
    return x > 0.0f ? s * x : s * a * (__expf(x) - 1.0f);
}

__device__ __forceinline__ unsigned short f2bf(float x) {
    uint32 u = __float_as_uint(x);
    uint32 r = (u + 0x7fff + ((u >> 16) & 1)) >> 16;   // RNE
    return (unsigned short)r;
}
__device__ __forceinline__ float bf_lo(uint32 g) { return __uint_as_float(g << 16); }
__device__ __forceinline__ float bf_hi(uint32 g) { return __uint_as_float(g & 0xffff0000u); }

// ---- repack W[128][128] fp32 -> B-fragment-ordered bf16 hi/lo ------------
// dest idx d = ((g)*128 + n)*8 + j  holds W[g*8+j][n],  g = c*4+quad
__global__ __launch_bounds__(256) void repack_w(const float* __restrict__ W1,
                                                const float* __restrict__ W2,
                                                ushort16* __restrict__ Wb) {
    const float* W = blockIdx.x ? W2 : W1;
    ushort16* oh = Wb + (size_t)blockIdx.x * 32768;
    ushort16* ol = oh + 16384;
    for (int d = threadIdx.x; d < 16384; d += 256) {
        int j = d & 7, nn = (d >> 3) & 127, g = d >> 10;
        float v = W[(g * 8 + j) * 128 + nn];
        uint32 hu = f2bf(v);
        float hv = __uint_as_float(hu << 16);
        oh[d] = (ushort16)hu;
        ol[d] = (ushort16)f2bf(v - hv);
    }
}

// ---- MFMA GEMM: hb[n,128](bf16) = X[n,128] @ W[128,128] + alpha dots -----
// 3-term split precision: x_hi*W_hi + x_lo*W_hi + x_hi*W_lo  (~fp32 exact)
// block = 4 waves * 32 rows = 128 rows; W (hi+lo) staged in 64 KB LDS.
__global__ __launch_bounds__(256) void gemm_mfma(const float* __restrict__ X,
                                                 const ushort16* __restrict__ Wbh,
                                                 const ushort16* __restrict__ Wbl,
                                                 const float* __restrict__ a_src,
                                                 const float* __restrict__ a_dst,
                                                 uint32* __restrict__ hb,
                                                 float* __restrict__ as_,
                                                 float* __restrict__ ad_, int n) {
    __shared__ __bf16 Wl[32768];   // 64 KB: [0..16383]=hi, [16384..]=lo
    const int tid = threadIdx.x;
    {
        const uint4* sh = (const uint4*)Wbh;
        const uint4* sl = (const uint4*)Wbl;
        uint4* dh = (uint4*)&Wl[0];
        uint4* dl = (uint4*)&Wl[16384];
        for (int i = tid; i < 2048; i += 256) { dh[i] = sh[i]; dl[i] = sl[i]; }
    }
    const int lane  = tid & 63;
    const int wid   = tid >> 6;
    const int col16 = lane & 15, quad = lane >> 4;
    const int rbase = blockIdx.x * 128 + wid * 32;

    // A fragments from global (coalesced float4), split hi/lo in registers
    bf16x8 ah[2][4], al[2][4];
    #pragma unroll
    for (int mt = 0; mt < 2; ++mt) {
        int r = rbase + mt * 16 + col16;
        bool ok = (r < n);
        const float* xp = X + (size_t)r * 128;
        #pragma unroll
        for (int c = 0; c < 4; ++c) {
            int k0 = c * 32 + quad * 8;
            float4 x0 = ok ? *(const float4*)(xp + k0)     : make_float4(0.f,0.f,0.f,0.f);
            float4 x1 = ok ? *(const float4*)(xp + k0 + 4) : make_float4(0.f,0.f,0.f,0.f);
            float xs[8] = {x0.x,x0.y,x0.z,x0.w,x1.x,x1.y,x1.z,x1.w};
            #pragma unroll
            for (int j = 0; j < 8; ++j) {
                __bf16 h = (__bf16)xs[j];
                ah[mt][c][j] = h;
                al[mt][c][j] = (__bf16)(xs[j] - (float)h);
            }
        }
    }
    __syncthreads();

    f32x4 acc[2][8];
    #pragma unroll
    for (int mt = 0; mt < 2; ++mt)
        #pragma unroll
        for (int t = 0; t < 8; ++t) acc[mt][t] = (f32x4)(0.0f);

    #pragma unroll
    for (int c = 0; c < 4; ++c) {
        #pragma unroll
        for (int t = 0; t < 8; ++t) {
            int off = (((c * 4 + quad) * 128) + t * 16 + col16) * 8;
            bf16x8 bh = *(const bf16x8*)&Wl[off];
            bf16x8 bl = *(const bf16x8*)&Wl[16384 + off];
            #pragma unroll
            for (int mt = 0; mt < 2; ++mt) {
                acc[mt][t] = __builtin_amdgcn_mfma_f32_16x16x32_bf16(ah[mt][c], bh, acc[mt][t], 0, 0, 0);
                acc[mt][t] = __builtin_amdgcn_mfma_f32_16x16x32_bf16(al[mt][c], bh, acc[mt][t], 0, 0, 0);
                acc[mt][t] = __builtin_amdgcn_mfma_f32_16x16x32_bf16(ah[mt][c], bl, acc[mt][t], 0, 0, 0);
            }
        }
    }

    // ---- epilogue 1: attention dots (fp32) via 16-lane reduction ----
    float asv[8], adv[8];
    #pragma unroll
    for (int t = 0; t < 8; ++t) { asv[t] = a_src[t * 16 + col16]; adv[t] = a_dst[t * 16 + col16]; }
    #pragma unroll
    for (int mt = 0; mt < 2; ++mt) {
        #pragma unroll
        for (int reg = 0; reg < 4; ++reg) {
            float s = 0.0f, d = 0.0f;
            #pragma unroll
            for (int t = 0; t < 8; ++t) {
                float v = acc[mt][t][reg];
                s += v * asv[t]; d += v * adv[t];
            }
            #pragma unroll
            for (int off = 1; off < 16; off <<= 1) {
                s += __shfl_xor(s, off);
                d += __shfl_xor(d, off);
            }
            int r = rbase + mt * 16 + quad * 4 + reg;
            if (col16 == 0 && r < n) { as_[r] = s; ad_[r] = d; }
        }
    }
    // ---- epilogue 2: pack bf16 pairs via neighbor shfl, store hb ----
    #pragma unroll
    for (int mt = 0; mt < 2; ++mt)
    #pragma unroll
    for (int t = 0; t < 8; ++t)
    #pragma unroll
    for (int reg = 0; reg < 4; ++reg) {
        float v = acc[mt][t][reg];
        float p = __shfl_xor(v, 1);
        int r = rbase + mt * 16 + quad * 4 + reg;
        if (!(col16 & 1) && r < n) {
            uint32 pk = (uint32)f2bf(v) | ((uint32)f2bf(p) << 16);
            hb[(size_t)r * 64 + t * 8 + (col16 >> 1)] = pk;
        }
    }
}

// ------------- bucket histogram over dst>>BSHIFT (LDS, then merge) --------
__global__ __launch_bounds__(256) void bucket_hist(const int* __restrict__ ei,
                                                   int* __restrict__ gcnt, int E, int TOT) {
    __shared__ int lh[MAXB];
    int t = threadIdx.x;
    lh[t] = 0;
    __syncthreads();
    int eb = blockIdx.x * PCHUNK;
    #pragma unroll
    for (int k = 0; k < PCHUNK / 256; ++k) {
        int e = eb + k * 256 + t;
        if (e < TOT) {
            int d = (e < E) ? ei[E + e] : e - E;
            atomicAdd(&lh[d >> BSHIFT], 1);
        }
    }
    __syncthreads();
    if (lh[t] > 0) atomicAdd(&gcnt[t], lh[t]);
}

// ------------- exclusive scan of bucket counts (single block) -------------
__global__ __launch_bounds__(256) void bucket_scan(const int* __restrict__ gcnt,
                                                   int* __restrict__ bstart,
                                                   int* __restrict__ gcursor, int NB, int TOT) {
    __shared__ int sh[256];
    int t = threadIdx.x;
    int v = (t < NB) ? gcnt[t] : 0;
    sh[t] = v;
    __syncthreads();
    for (int off = 1; off < 256; off <<= 1) {
        int add = (t >= off) ? sh[t - off] : 0;
        __syncthreads();
        sh[t] += add;
        __syncthreads();
    }
    int ex = sh[t] - v;
    if (t < NB) { bstart[t] = ex; gcursor[t] = ex; }
    if (t == 0) bstart[NB] = TOT;
}

// ------------- partition edges into buckets (LDS counting sort) -----------
__global__ __launch_bounds__(256) void partition_edges(const int* __restrict__ ei,
                                                       int* __restrict__ gcursor,
                                                       uint32* __restrict__ tmp,
                                                       int E, int TOT) {
    __shared__ int lcnt[MAXB];
    __shared__ int lstart[MAXB];
    __shared__ int lcur[MAXB];
    __shared__ int gbase[MAXB];
    __shared__ uint32 staged[PCHUNK];
    __shared__ unsigned char bslot[PCHUNK];
    int t = threadIdx.x;
    int eb = blockIdx.x * PCHUNK;
    int sreg[16], dreg[16];
    #pragma unroll
    for (int k = 0; k < 16; ++k) {
        int e = eb + k * 256 + t;
        if (e < TOT) {
            if (e < E) { sreg[k] = ei[e]; dreg[k] = ei[E + e]; }
            else       { sreg[k] = dreg[k] = e - E; }
        } else dreg[k] = -1;
    }
    lcnt[t] = 0;
    __syncthreads();
    #pragma unroll
    for (int k = 0; k < 16; ++k)
        if (dreg[k] >= 0) atomicAdd(&lcnt[dreg[k] >> BSHIFT], 1);
    __syncthreads();
    int v = lcnt[t];
    lstart[t] = v;
    __syncthreads();
    for (int off = 1; off < 256; off <<= 1) {
        int add = (t >= off) ? lstart[t - off] : 0;
        __syncthreads();
        lstart[t] += add;
        __syncthreads();
    }
    int ex = lstart[t] - v;
    __syncthreads();
    lstart[t] = ex;
    lcur[t] = ex;
    if (v > 0) gbase[t] = atomicAdd(&gcursor[t], v);
    __syncthreads();
    #pragma unroll
    for (int k = 0; k < 16; ++k) {
        int d = dreg[k];
        if (d >= 0) {
            int b = d >> BSHIFT;
            int p = atomicAdd(&lcur[b], 1);
            staged[p] = ((uint32)(d & (BSIZE - 1)) << 17) | (uint32)sreg[k];
            bslot[p] = (unsigned char)b;
        }
    }
    __syncthreads();
    int nvalid = TOT - eb; if (nvalid > PCHUNK) nvalid = PCHUNK;
    for (int i = t; i < nvalid; i += 256) {
        int b = bslot[i];
        tmp[gbase[b] + (i - lstart[b])] = staged[i];
    }
}

// ------------- per-bucket: per-node scan -> rowptr + col scatter ----------
__global__ __launch_bounds__(256) void bucket_build(const uint32* __restrict__ tmp,
                                                    const int* __restrict__ bstart,
                                                    int* __restrict__ rowptr,
                                                    int* __restrict__ col,
                                                    int N, int TOT, int NB) {
    __shared__ int cnt[BSIZE];
    __shared__ int sums[256];
    int b = blockIdx.x, t = threadIdx.x;
    int lo = b << BSHIFT;
    int nn = N - lo; if (nn > BSIZE) nn = BSIZE;
    cnt[t] = 0; cnt[t + 256] = 0;
    __syncthreads();
    int ebeg = bstart[b], eend = bstart[b + 1];
    for (int i = ebeg + t; i < eend; i += 256)
        atomicAdd(&cnt[tmp[i] >> 17], 1);
    __syncthreads();
    int c0 = cnt[2 * t], c1 = cnt[2 * t + 1];
    int s2 = c0 + c1;
    sums[t] = s2;
    __syncthreads();
    for (int off = 1; off < 256; off <<= 1) {
        int add = (t >= off) ? sums[t - off] : 0;
        __syncthreads();
        sums[t] += add;
        __syncthreads();
    }
    int ex = sums[t] - s2;
    int st0 = ebeg + ex, st1 = st0 + c0;
    if (2 * t < nn)     rowptr[lo + 2 * t] = st0;
    if (2 * t + 1 < nn) rowptr[lo + 2 * t + 1] = st1;
    cnt[2 * t] = st0; cnt[2 * t + 1] = st1;
    __syncthreads();
    for (int i = ebeg + t; i < eend; i += 256) {
        uint32 u = tmp[i];
        int p = atomicAdd(&cnt[u >> 17], 1);
        col[p] = (int)(u & 0x1FFFFu);
    }
    if (b == NB - 1 && t == 0) rowptr[N] = TOT;
}

// --------- fused GAT per-dst: softmax + bf16 gather agg + bias + selu ------
__global__ __launch_bounds__(256) void gat_csr2(const int* __restrict__ rowptr,
                                                const int* __restrict__ col,
                                                const uint32* __restrict__ hb,
                                                const float* __restrict__ as_,
                                                const float* __restrict__ ad_,
                                                const float* __restrict__ bias,
                                                float* __restrict__ outb, int n) {
    __shared__ float wsh[4][64];
    __shared__ int   ssh[4][64];
    int wid  = threadIdx.x >> 6;
    int lane = threadIdx.x & 63;
    int node = blockIdx.x * 4 + wid;
    if (node >= n) return;
    int beg = rowptr[node], end = rowptr[node + 1];
    float add = ad_[node];
    float m = -INFINITY, s = 0.0f, accx = 0.0f, accy = 0.0f;
    for (int c = beg; c < end; c += 64) {
        int j = c + lane;
        int cntv = min(64, end - c);
        int srcn = (j < end) ? col[j] : 0;
        float v = (j < end) ? (as_[srcn] + add) : -INFINITY;
        v = (v > 0.0f) ? v : NEG_SLOPE * v;
        float cm = v;
        #pragma unroll
        for (int off = 32; off > 0; off >>= 1) cm = fmaxf(cm, __shfl_xor(cm, off));
        float nm = fmaxf(m, cm);
        float w = (j < end) ? __expf(v - nm) : 0.0f;
        float ws = w;
        #pragma unroll
        for (int off = 32; off > 0; off >>= 1) ws += __shfl_xor(ws, off);
        float scale = (m == -INFINITY) ? 0.0f : __expf(m - nm);
        s = s * scale + ws;
        accx *= scale; accy *= scale;
        wsh[wid][lane] = w;
        ssh[wid][lane] = srcn;
        int t = 0;
        for (; t + 8 <= cntv; t += 8) {
            int   sr[8]; float wr[8]; uint32 g[8];
            #pragma unroll
            for (int q = 0; q < 8; ++q) { sr[q] = ssh[wid][t + q]; wr[q] = wsh[wid][t + q]; }
            #pragma unroll
            for (int q = 0; q < 8; ++q) g[q] = hb[(size_t)sr[q] * 64 + lane];
            #pragma unroll
            for (int q = 0; q < 8; ++q) {
                accx += wr[q] * bf_lo(g[q]);
                accy += wr[q] * bf_hi(g[q]);
            }
        }
        for (; t < cntv; ++t) {
            int sn = ssh[wid][t];
            float wt = wsh[wid][t];
            uint32 g = hb[(size_t)sn * 64 + lane];
            accx += wt * bf_lo(g);
            accy += wt * bf_hi(g);
        }
        m = nm;
    }
    float inv = 1.0f / s;
    float2 r;
    r.x = selu_f(accx * inv + bias[lane * 2 + 0]);
    r.y = selu_f(accy * inv + bias[lane * 2 + 1]);
    *(float2*)&outb[(size_t)node * 128 + lane * 2] = r;
}

// ------------- pooling: batch sorted -> per-block running sums, flush -----
#define NPB 128
__global__ __launch_bounds__(128) void pool_kernel(const float* __restrict__ act,
                                                   const int* __restrict__ batch,
                                                   float* __restrict__ sums,
                                                   float* __restrict__ cnts, int n) {
    int t = threadIdx.x;
    int base = blockIdx.x * NPB;
    float acc = 0.0f, c = 0.0f;
    int curg = -1;
    for (int i = 0; i < NPB; ++i) {
        int node = base + i;
        if (node >= n) break;
        int g = batch[node];
        if (g != curg) {
            if (curg >= 0) {
                unsafeAtomicAdd(&sums[curg * 128 + t], acc);
                if (t == 0) unsafeAtomicAdd(&cnts[curg], c);
            }
            curg = g; acc = 0.0f; c = 0.0f;
        }
        acc += act[(size_t)node * 128 + t];
        c += 1.0f;
    }
    if (curg >= 0) {
        unsafeAtomicAdd(&sums[curg * 128 + t], acc);
        if (t == 0) unsafeAtomicAdd(&cnts[curg], c);
    }
}

// ------------- head: selu(pool) -> fc1+selu -> fc2 -> log_softmax ---------
__global__ __launch_bounds__(128) void head_kernel(const float* __restrict__ sums,
                                                   const float* __restrict__ cnts,
                                                   const float* __restrict__ Wfc1,
                                                   const float* __restrict__ bfc1,
                                                   const float* __restrict__ Wfc2,
                                                   const float* __restrict__ bfc2,
                                                   float* __restrict__ out) {
    __shared__ float p[128];
    __shared__ float q[64];
    __shared__ float l[10];
    __shared__ float red[2];
    int g = blockIdx.x, t = threadIdx.x;
    float d = fmaxf(cnts[g], 1.0f);
    p[t] = selu_f(sums[g * 128 + t] / d);
    __syncthreads();
    if (t < 64) {
        float a = bfc1[t];
        #pragma unroll 8
        for (int k = 0; k < 128; ++k) a += p[k] * Wfc1[k * 64 + t];
        q[t] = selu_f(a);
    }
    __syncthreads();
    if (t < 10) {
        float a = bfc2[t];
        #pragma unroll
        for (int k = 0; k < 64; ++k) a += q[k] * Wfc2[k * 10 + t];
        l[t] = a;
    }
    __syncthreads();
    if (t == 0) {
        float m = l[0];
        for (int c = 1; c < 10; ++c) m = fmaxf(m, l[c]);
        float sum = 0.0f;
        for (int c = 0; c < 10; ++c) sum += __expf(l[c] - m);
        red[0] = m; red[1] = logf(sum);
    }
    __syncthreads();
    if (t < 10) out[g * 10 + t] = l[t] - red[0] - red[1];
}

extern "C" void kernel_launch(void* const* d_in, const int* in_sizes, int n_in,
                              void* d_out, int out_size, void* d_ws, size_t ws_size,
                              hipStream_t stream) {
    const float* x      = (const float*)d_in[0];
    const int*   ei     = (const int*)d_in[1];
    const int*   batch  = (const int*)d_in[2];
    const float* W1     = (const float*)d_in[3];
    const float* asrc1  = (const float*)d_in[4];
    const float* adst1  = (const float*)d_in[5];
    const float* b1     = (const float*)d_in[6];
    const float* W2     = (const float*)d_in[7];
    const float* asrc2  = (const float*)d_in[8];
    const float* adst2  = (const float*)d_in[9];
    const float* b2     = (const float*)d_in[10];
    const float* Wfc1   = (const float*)d_in[11];
    const float* bfc1   = (const float*)d_in[12];
    const float* Wfc2   = (const float*)d_in[13];
    const float* bfc2   = (const float*)d_in[14];
    float* out = (float*)d_out;

    const int N = in_sizes[0] / 128;
    const int E = in_sizes[1] / 2;
    const int G = out_size / 10;
    const int TOT = E + N;
    const int NB = ((N - 1) >> BSHIFT) + 1;

    // workspace layout
    uint32* hb    = (uint32*)d_ws;                   // N*64  (bf16 h)
    uint32* tmp   = hb + (size_t)N * 64;             // TOT
    float* bufA   = (float*)(tmp + TOT);             // N*128 fp32
    float* as_    = bufA + (size_t)N * 128;          // N
    float* ad_    = as_ + N;                         // N
    float* sums   = ad_ + N;                         // G*128
    float* cnts   = sums + (size_t)G * 128;          // G
    int*   rowptr = (int*)(cnts + G);                // N+1
    int*   gcnt   = rowptr + (N + 2);                // 256
    int*   bstart = gcnt + MAXB;                     // 257
    int*   gcursor= bstart + MAXB + 1;               // 256
    int*   col    = gcursor + MAXB;                  // TOT
    ushort16* Wb  = (ushort16*)(((uintptr_t)(col + TOT) + 255) & ~(uintptr_t)255);
    // Wb: 2 layers x (16384 hi + 16384 lo) ushorts = 128 KB

    const int gemmGrid = (N + 127) / 128;
    const int partGrid = (TOT + PCHUNK - 1) / PCHUNK;
    const int poolGrid = (N + NPB - 1) / NPB;

    // ---------------- weight repack + CSR build ----------------
    repack_w<<<2, 256, 0, stream>>>(W1, W2, Wb);
    hipMemsetAsync(gcnt, 0, MAXB * 4, stream);
    bucket_hist<<<partGrid, 256, 0, stream>>>(ei, gcnt, E, TOT);
    bucket_scan<<<1, 256, 0, stream>>>(gcnt, bstart, gcursor, NB, TOT);
    partition_edges<<<partGrid, 256, 0, stream>>>(ei, gcursor, tmp, E, TOT);
    bucket_build<<<NB, 256, 0, stream>>>(tmp, bstart, rowptr, col, N, TOT, NB);

    // ---------------- layer 1 ----------------
    gemm_mfma<<<gemmGrid, 256, 0, stream>>>(x, Wb, Wb + 16384, asrc1, adst1, hb, as_, ad_, N);
    gat_csr2<<<(N + 3) / 4, 256, 0, stream>>>(rowptr, col, hb, as_, ad_, b1, bufA, N);

    // ---------------- layer 2 ----------------
    gemm_mfma<<<gemmGrid, 256, 0, stream>>>(bufA, Wb + 32768, Wb + 49152, asrc2, adst2, hb, as_, ad_, N);
    gat_csr2<<<(N + 3) / 4, 256, 0, stream>>>(rowptr, col, hb, as_, ad_, b2, bufA, N);

    // ---------------- pool + head ----------------
    hipMemsetAsync(sums, 0, (size_t)G * 128 * 4, stream);
    hipMemsetAsync(cnts, 0, (size_t)G * 4, stream);
    pool_kernel<<<poolGrid, 128, 0, stream>>>(bufA, batch, sums, cnts, N);
    head_kernel<<<G, 128, 0, stream>>>(sums, cnts, Wfc1, bfc1, Wfc2, bfc2, out);
}

// Round 6
// 417.807 us; speedup vs baseline: 8.2594x; 1.1093x over previous
//
#include <hip/hip_runtime.h>
#include <hip/hip_bf16.h>

#define NEG_SLOPE 0.2f
typedef unsigned int uint32;

#define BSHIFT 9
#define BSIZE 512          // nodes per bucket
#define MAXB 256           // max buckets (N < 131072)
#define PCHUNK 4096        // edges per partition block

typedef __attribute__((ext_vector_type(8))) __bf16 bf16x8;
typedef __attribute__((ext_vector_type(4))) float f32x4;

__device__ __forceinline__ float selu_f(float x) {
    const float a = 1.6732632423543772f, s = 1.0507009873554805f;
    return x > 0.0f ? s * x : s * a * (__expf(x) - 1.0f);
}

__device__ __forceinline__ unsigned short f2bf(float x) {
    uint32 u = __float_as_uint(x);
    uint32 r = (u + 0x7fff + ((u >> 16) & 1)) >> 16;   // RNE
    return (unsigned short)r;
}
__device__ __forceinline__ float bf_lo(uint32 g) { return __uint_as_float(g << 16); }
__device__ __forceinline__ float bf_hi(uint32 g) { return __uint_as_float(g & 0xffff0000u); }

// ---- repack W[128][128] fp32 -> B-fragment-ordered bf16 hi/lo ------------
// dest idx d = (g*128 + n)*8 + j  holds W[g*8+j][n],  g = c*4+quad
__global__ __launch_bounds__(256) void repack_w(const float* __restrict__ W1,
                                                const float* __restrict__ W2,
                                                unsigned short* __restrict__ Wb) {
    const float* W = blockIdx.x ? W2 : W1;
    unsigned short* oh = Wb + (size_t)blockIdx.x * 32768;
    unsigned short* ol = oh + 16384;
    for (int d = threadIdx.x; d < 16384; d += 256) {
        int j = d & 7, nn = (d >> 3) & 127, g = d >> 10;
        float v = W[(g * 8 + j) * 128 + nn];
        uint32 hu = f2bf(v);
        float hv = __uint_as_float(hu << 16);
        oh[d] = (unsigned short)hu;
        ol[d] = f2bf(v - hv);
    }
}

// ---- shared MFMA core: A(bf16) x (B_hi + B_lo), 128 rows/block -----------
// epilogue: fp32 attention dots + packed bf16 h store
__device__ __forceinline__ void gemm_core(const bf16x8 ah[2][4],
                                          const __bf16* Wl,
                                          const float* a_src, const float* a_dst,
                                          uint32* hb, float* as_, float* ad_,
                                          int rbase, int n, int col16, int quad) {
    f32x4 acc[2][8];
    #pragma unroll
    for (int mt = 0; mt < 2; ++mt)
        #pragma unroll
        for (int t = 0; t < 8; ++t) acc[mt][t] = (f32x4)(0.0f);

    #pragma unroll
    for (int c = 0; c < 4; ++c) {
        #pragma unroll
        for (int t = 0; t < 8; ++t) {
            int off = (((c * 4 + quad) * 128) + t * 16 + col16) * 8;
            bf16x8 bh = *(const bf16x8*)&Wl[off];
            bf16x8 bl = *(const bf16x8*)&Wl[16384 + off];
            #pragma unroll
            for (int mt = 0; mt < 2; ++mt) {
                acc[mt][t] = __builtin_amdgcn_mfma_f32_16x16x32_bf16(ah[mt][c], bh, acc[mt][t], 0, 0, 0);
                acc[mt][t] = __builtin_amdgcn_mfma_f32_16x16x32_bf16(ah[mt][c], bl, acc[mt][t], 0, 0, 0);
            }
        }
    }
    // attention dots (fp32) via 16-lane reduction
    float asv[8], adv[8];
    #pragma unroll
    for (int t = 0; t < 8; ++t) { asv[t] = a_src[t * 16 + col16]; adv[t] = a_dst[t * 16 + col16]; }
    #pragma unroll
    for (int mt = 0; mt < 2; ++mt) {
        #pragma unroll
        for (int reg = 0; reg < 4; ++reg) {
            float s = 0.0f, d = 0.0f;
            #pragma unroll
            for (int t = 0; t < 8; ++t) {
                float v = acc[mt][t][reg];
                s += v * asv[t]; d += v * adv[t];
            }
            #pragma unroll
            for (int off = 1; off < 16; off <<= 1) {
                s += __shfl_xor(s, off);
                d += __shfl_xor(d, off);
            }
            int r = rbase + mt * 16 + quad * 4 + reg;
            if (col16 == 0 && r < n) { as_[r] = s; ad_[r] = d; }
        }
    }
    // pack bf16 pairs via neighbor shfl, store hb
    #pragma unroll
    for (int mt = 0; mt < 2; ++mt)
    #pragma unroll
    for (int t = 0; t < 8; ++t)
    #pragma unroll
    for (int reg = 0; reg < 4; ++reg) {
        float v = acc[mt][t][reg];
        float p = __shfl_xor(v, 1);
        int r = rbase + mt * 16 + quad * 4 + reg;
        if (!(col16 & 1) && r < n) {
            uint32 pk = (uint32)f2bf(v) | ((uint32)f2bf(p) << 16);
            hb[(size_t)r * 64 + t * 8 + (col16 >> 1)] = pk;
        }
    }
}

__global__ __launch_bounds__(256) void gemm_mfma_f32(const float* __restrict__ X,
                                                     const unsigned short* __restrict__ Wbh,
                                                     const float* __restrict__ a_src,
                                                     const float* __restrict__ a_dst,
                                                     uint32* __restrict__ hb,
                                                     float* __restrict__ as_,
                                                     float* __restrict__ ad_, int n) {
    __shared__ __bf16 Wl[32768];   // 64 KB hi+lo
    const int tid = threadIdx.x;
    {
        const uint4* sw = (const uint4*)Wbh;
        uint4* dw = (uint4*)Wl;
        for (int i = tid; i < 4096; i += 256) dw[i] = sw[i];
    }
    const int lane = tid & 63, wid = tid >> 6;
    const int col16 = lane & 15, quad = lane >> 4;
    const int rbase = blockIdx.x * 128 + wid * 32;
    bf16x8 ah[2][4];
    #pragma unroll
    for (int mt = 0; mt < 2; ++mt) {
        int r = rbase + mt * 16 + col16;
        bool ok = (r < n);
        const float* xp = X + (size_t)r * 128;
        #pragma unroll
        for (int c = 0; c < 4; ++c) {
            int k0 = c * 32 + quad * 8;
            float4 x0 = ok ? *(const float4*)(xp + k0)     : make_float4(0.f,0.f,0.f,0.f);
            float4 x1 = ok ? *(const float4*)(xp + k0 + 4) : make_float4(0.f,0.f,0.f,0.f);
            float xs[8] = {x0.x,x0.y,x0.z,x0.w,x1.x,x1.y,x1.z,x1.w};
            #pragma unroll
            for (int j = 0; j < 8; ++j) ah[mt][c][j] = (__bf16)xs[j];
        }
    }
    __syncthreads();
    gemm_core(ah, Wl, a_src, a_dst, hb, as_, ad_, rbase, n, col16, quad);
}

__global__ __launch_bounds__(256) void gemm_mfma_bf16(const __bf16* __restrict__ X,
                                                      const unsigned short* __restrict__ Wbh,
                                                      const float* __restrict__ a_src,
                                                      const float* __restrict__ a_dst,
                                                      uint32* __restrict__ hb,
                                                      float* __restrict__ as_,
                                                      float* __restrict__ ad_, int n) {
    __shared__ __bf16 Wl[32768];
    const int tid = threadIdx.x;
    {
        const uint4* sw = (const uint4*)Wbh;
        uint4* dw = (uint4*)Wl;
        for (int i = tid; i < 4096; i += 256) dw[i] = sw[i];
    }
    const int lane = tid & 63, wid = tid >> 6;
    const int col16 = lane & 15, quad = lane >> 4;
    const int rbase = blockIdx.x * 128 + wid * 32;
    bf16x8 ah[2][4];
    const bf16x8 zz = (bf16x8)((__bf16)0.0f);
    #pragma unroll
    for (int mt = 0; mt < 2; ++mt) {
        int r = rbase + mt * 16 + col16;
        bool ok = (r < n);
        const __bf16* xp = X + (size_t)r * 128;
        #pragma unroll
        for (int c = 0; c < 4; ++c)
            ah[mt][c] = ok ? *(const bf16x8*)(xp + c * 32 + quad * 8) : zz;
    }
    __syncthreads();
    gemm_core(ah, Wl, a_src, a_dst, hb, as_, ad_, rbase, n, col16, quad);
}

// ------------- bucket histogram over dst>>BSHIFT --------------------------
__global__ __launch_bounds__(256) void bucket_hist(const int* __restrict__ ei,
                                                   int* __restrict__ gcnt, int E, int TOT) {
    __shared__ int lh[MAXB];
    int t = threadIdx.x;
    lh[t] = 0;
    __syncthreads();
    int eb = blockIdx.x * PCHUNK;
    #pragma unroll
    for (int k = 0; k < PCHUNK / 256; ++k) {
        int e = eb + k * 256 + t;
        if (e < TOT) {
            int d = (e < E) ? ei[E + e] : e - E;
            atomicAdd(&lh[d >> BSHIFT], 1);
        }
    }
    __syncthreads();
    if (lh[t] > 0) atomicAdd(&gcnt[t], lh[t]);
}

// ------------- exclusive scan of bucket counts (single block) -------------
__global__ __launch_bounds__(256) void bucket_scan(const int* __restrict__ gcnt,
                                                   int* __restrict__ bstart,
                                                   int* __restrict__ gcursor, int NB, int TOT) {
    __shared__ int sh[256];
    int t = threadIdx.x;
    int v = (t < NB) ? gcnt[t] : 0;
    sh[t] = v;
    __syncthreads();
    for (int off = 1; off < 256; off <<= 1) {
        int add = (t >= off) ? sh[t - off] : 0;
        __syncthreads();
        sh[t] += add;
        __syncthreads();
    }
    int ex = sh[t] - v;
    if (t < NB) { bstart[t] = ex; gcursor[t] = ex; }
    if (t == 0) bstart[NB] = TOT;
}

// ------------- partition edges into buckets (LDS counting sort) -----------
__global__ __launch_bounds__(256) void partition_edges(const int* __restrict__ ei,
                                                       int* __restrict__ gcursor,
                                                       uint32* __restrict__ tmp,
                                                       int E, int TOT) {
    __shared__ int lcnt[MAXB];
    __shared__ int lstart[MAXB];
    __shared__ int lcur[MAXB];
    __shared__ int gbase[MAXB];
    __shared__ uint32 staged[PCHUNK];
    __shared__ unsigned char bslot[PCHUNK];
    int t = threadIdx.x;
    int eb = blockIdx.x * PCHUNK;
    int sreg[16], dreg[16];
    #pragma unroll
    for (int k = 0; k < 16; ++k) {
        int e = eb + k * 256 + t;
        if (e < TOT) {
            if (e < E) { sreg[k] = ei[e]; dreg[k] = ei[E + e]; }
            else       { sreg[k] = dreg[k] = e - E; }
        } else dreg[k] = -1;
    }
    lcnt[t] = 0;
    __syncthreads();
    #pragma unroll
    for (int k = 0; k < 16; ++k)
        if (dreg[k] >= 0) atomicAdd(&lcnt[dreg[k] >> BSHIFT], 1);
    __syncthreads();
    int v = lcnt[t];
    lstart[t] = v;
    __syncthreads();
    for (int off = 1; off < 256; off <<= 1) {
        int add = (t >= off) ? lstart[t - off] : 0;
        __syncthreads();
        lstart[t] += add;
        __syncthreads();
    }
    int ex = lstart[t] - v;
    __syncthreads();
    lstart[t] = ex;
    lcur[t] = ex;
    if (v > 0) gbase[t] = atomicAdd(&gcursor[t], v);
    __syncthreads();
    #pragma unroll
    for (int k = 0; k < 16; ++k) {
        int d = dreg[k];
        if (d >= 0) {
            int b = d >> BSHIFT;
            int p = atomicAdd(&lcur[b], 1);
            staged[p] = ((uint32)(d & (BSIZE - 1)) << 17) | (uint32)sreg[k];
            bslot[p] = (unsigned char)b;
        }
    }
    __syncthreads();
    int nvalid = TOT - eb; if (nvalid > PCHUNK) nvalid = PCHUNK;
    for (int i = t; i < nvalid; i += 256) {
        int b = bslot[i];
        tmp[gbase[b] + (i - lstart[b])] = staged[i];
    }
}

// ------------- per-bucket: per-node scan -> rowptr + col scatter ----------
__global__ __launch_bounds__(256) void bucket_build(const uint32* __restrict__ tmp,
                                                    const int* __restrict__ bstart,
                                                    int* __restrict__ rowptr,
                                                    int* __restrict__ col,
                                                    int N, int TOT, int NB) {
    __shared__ int cnt[BSIZE];
    __shared__ int sums[256];
    int b = blockIdx.x, t = threadIdx.x;
    int lo = b << BSHIFT;
    int nn = N - lo; if (nn > BSIZE) nn = BSIZE;
    cnt[t] = 0; cnt[t + 256] = 0;
    __syncthreads();
    int ebeg = bstart[b], eend = bstart[b + 1];
    for (int i = ebeg + t; i < eend; i += 256)
        atomicAdd(&cnt[tmp[i] >> 17], 1);
    __syncthreads();
    int c0 = cnt[2 * t], c1 = cnt[2 * t + 1];
    int s2 = c0 + c1;
    sums[t] = s2;
    __syncthreads();
    for (int off = 1; off < 256; off <<= 1) {
        int add = (t >= off) ? sums[t - off] : 0;
        __syncthreads();
        sums[t] += add;
        __syncthreads();
    }
    int ex = sums[t] - s2;
    int st0 = ebeg + ex, st1 = st0 + c0;
    if (2 * t < nn)     rowptr[lo + 2 * t] = st0;
    if (2 * t + 1 < nn) rowptr[lo + 2 * t + 1] = st1;
    cnt[2 * t] = st0; cnt[2 * t + 1] = st1;
    __syncthreads();
    for (int i = ebeg + t; i < eend; i += 256) {
        uint32 u = tmp[i];
        int p = atomicAdd(&cnt[u >> 17], 1);
        col[p] = (int)(u & 0x1FFFFu);
    }
    if (b == NB - 1 && t == 0) rowptr[N] = TOT;
}

// --------- fused GAT: 2 nodes/wave, softmax + bf16 gather + selu ----------
__global__ __launch_bounds__(256) void gat_csr3(const int* __restrict__ rowptr,
                                                const int* __restrict__ col,
                                                const uint2* __restrict__ hb2,
                                                const float* __restrict__ as_,
                                                const float* __restrict__ ad_,
                                                const float* __restrict__ bias,
                                                uint2* __restrict__ outb, int n) {
    __shared__ float wsh[4][2][32];
    __shared__ int   ssh[4][2][32];
    const int wid = threadIdx.x >> 6;
    const int lane = threadIdx.x & 63;
    const int sub = lane >> 5, l = lane & 31;
    const int node = blockIdx.x * 8 + wid * 2 + sub;
    const bool valid = node < n;
    int beg = 0, end = 0;
    if (valid) { beg = rowptr[node]; end = rowptr[node + 1]; }
    float add = valid ? ad_[node] : 0.0f;
    int deg = end - beg;
    int mdeg = max(deg, __shfl_xor(deg, 32));
    float m = -INFINITY, s = 0.0f;
    float a0 = 0.f, a1 = 0.f, a2 = 0.f, a3 = 0.f;
    for (int cb = 0; cb < mdeg; cb += 32) {
        int j = beg + cb + l;
        bool eok = (j < end);
        int srcn = eok ? col[j] : 0;
        float v = eok ? (as_[srcn] + add) : -INFINITY;
        v = (v > 0.0f) ? v : NEG_SLOPE * v;
        float cm = v;
        #pragma unroll
        for (int off = 16; off > 0; off >>= 1) cm = fmaxf(cm, __shfl_xor(cm, off));
        float nm = fmaxf(m, cm);
        float w = eok ? __expf(v - nm) : 0.0f;
        float ws = w;
        #pragma unroll
        for (int off = 16; off > 0; off >>= 1) ws += __shfl_xor(ws, off);
        float scale = (m == -INFINITY) ? 0.0f : __expf(m - nm);
        s = s * scale + ws;
        a0 *= scale; a1 *= scale; a2 *= scale; a3 *= scale;
        wsh[wid][sub][l] = w;
        ssh[wid][sub][l] = srcn;   // same-wave LDS write->read, in order
        int cnt = end - beg - cb;
        cnt = (cnt > 32) ? 32 : (cnt < 0 ? 0 : cnt);
        int t = 0;
        for (; t + 8 <= cnt; t += 8) {
            int sr[8]; float wr[8]; uint2 g[8];
            #pragma unroll
            for (int q = 0; q < 8; ++q) { sr[q] = ssh[wid][sub][t + q]; wr[q] = wsh[wid][sub][t + q]; }
            #pragma unroll
            for (int q = 0; q < 8; ++q) g[q] = hb2[(uint32)sr[q] * 32u + l];
            #pragma unroll
            for (int q = 0; q < 8; ++q) {
                a0 += wr[q] * bf_lo(g[q].x); a1 += wr[q] * bf_hi(g[q].x);
                a2 += wr[q] * bf_lo(g[q].y); a3 += wr[q] * bf_hi(g[q].y);
            }
        }
        for (; t < cnt; ++t) {
            int sn = ssh[wid][sub][t];
            float wt = wsh[wid][sub][t];
            uint2 g = hb2[(uint32)sn * 32u + l];
            a0 += wt * bf_lo(g.x); a1 += wt * bf_hi(g.x);
            a2 += wt * bf_lo(g.y); a3 += wt * bf_hi(g.y);
        }
        m = nm;
    }
    if (valid) {
        float inv = 1.0f / s;
        float4 bv = *(const float4*)&bias[l * 4];
        float r0 = selu_f(a0 * inv + bv.x);
        float r1 = selu_f(a1 * inv + bv.y);
        float r2 = selu_f(a2 * inv + bv.z);
        float r3 = selu_f(a3 * inv + bv.w);
        uint2 o;
        o.x = (uint32)f2bf(r0) | ((uint32)f2bf(r1) << 16);
        o.y = (uint32)f2bf(r2) | ((uint32)f2bf(r3) << 16);
        outb[(uint32)node * 32u + l] = o;
    }
}

// ------------- per-graph node ranges from sorted batch --------------------
__global__ __launch_bounds__(256) void graph_bounds(const int* __restrict__ batch,
                                                    int* __restrict__ gstart, int n, int G) {
    int i = blockIdx.x * 256 + threadIdx.x;
    if (i >= n) return;
    int b = batch[i];
    int bp = (i == 0) ? -1 : batch[i - 1];
    for (int q = bp + 1; q <= b; ++q) gstart[q] = i;
    if (i == n - 1)
        for (int q = b + 1; q <= G; ++q) gstart[q] = n;
}

// ------------- fused mean-pool + head, one block per graph ----------------
__global__ __launch_bounds__(128) void pool_head(const uint32* __restrict__ act,
                                                 const int* __restrict__ gstart,
                                                 const float* __restrict__ Wfc1,
                                                 const float* __restrict__ bfc1,
                                                 const float* __restrict__ Wfc2,
                                                 const float* __restrict__ bfc2,
                                                 float* __restrict__ out) {
    __shared__ float part[128][2];
    __shared__ float p[128];
    __shared__ float q[64];
    __shared__ float l[10];
    __shared__ float red[2];
    int g = blockIdx.x, t = threadIdx.x;
    int lo = gstart[g], hi = gstart[g + 1];
    int half = t >> 6, u = t & 63;
    float acc0 = 0.f, acc1 = 0.f;
    for (int nd = lo + half; nd < hi; nd += 2) {
        uint32 gv = act[(uint32)nd * 64u + u];
        acc0 += bf_lo(gv); acc1 += bf_hi(gv);
    }
    part[t][0] = acc0; part[t][1] = acc1;
    __syncthreads();
    if (half == 0) {
        float c = fmaxf((float)(hi - lo), 1.0f);
        p[2 * u]     = selu_f((acc0 + part[t + 64][0]) / c);
        p[2 * u + 1] = selu_f((acc1 + part[t + 64][1]) / c);
    }
    __syncthreads();
    if (t < 64) {
        float a = bfc1[t];
        #pragma unroll 8
        for (int k = 0; k < 128; ++k) a += p[k] * Wfc1[k * 64 + t];
        q[t] = selu_f(a);
    }
    __syncthreads();
    if (t < 10) {
        float a = bfc2[t];
        #pragma unroll
        for (int k = 0; k < 64; ++k) a += q[k] * Wfc2[k * 10 + t];
        l[t] = a;
    }
    __syncthreads();
    if (t == 0) {
        float mx = l[0];
        for (int c = 1; c < 10; ++c) mx = fmaxf(mx, l[c]);
        float sum = 0.0f;
        for (int c = 0; c < 10; ++c) sum += __expf(l[c] - mx);
        red[0] = mx; red[1] = logf(sum);
    }
    __syncthreads();
    if (t < 10) out[g * 10 + t] = l[t] - red[0] - red[1];
}

extern "C" void kernel_launch(void* const* d_in, const int* in_sizes, int n_in,
                              void* d_out, int out_size, void* d_ws, size_t ws_size,
                              hipStream_t stream) {
    const float* x      = (const float*)d_in[0];
    const int*   ei     = (const int*)d_in[1];
    const int*   batch  = (const int*)d_in[2];
    const float* W1     = (const float*)d_in[3];
    const float* asrc1  = (const float*)d_in[4];
    const float* adst1  = (const float*)d_in[5];
    const float* b1     = (const float*)d_in[6];
    const float* W2     = (const float*)d_in[7];
    const float* asrc2  = (const float*)d_in[8];
    const float* adst2  = (const float*)d_in[9];
    const float* b2     = (const float*)d_in[10];
    const float* Wfc1   = (const float*)d_in[11];
    const float* bfc1   = (const float*)d_in[12];
    const float* Wfc2   = (const float*)d_in[13];
    const float* bfc2   = (const float*)d_in[14];
    float* out = (float*)d_out;

    const int N = in_sizes[0] / 128;
    const int E = in_sizes[1] / 2;
    const int G = out_size / 10;
    const int TOT = E + N;
    const int NB = ((N - 1) >> BSHIFT) + 1;

    // workspace layout
    uint32* hb    = (uint32*)d_ws;                   // N*64  (bf16 h, gather buf)
    uint32* h2b   = hb + (size_t)N * 64;             // N*64  (bf16 layer outputs)
    uint32* tmp   = h2b + (size_t)N * 64;            // TOT
    float* as_    = (float*)(tmp + TOT);             // N
    float* ad_    = as_ + N;                         // N
    int*   gstart = (int*)(ad_ + N);                 // G+1
    int*   rowptr = gstart + (G + 2);                // N+1
    int*   gcnt   = rowptr + (N + 2);                // 256
    int*   bstart = gcnt + MAXB;                     // 257
    int*   gcursor= bstart + MAXB + 1;               // 256
    int*   col    = gcursor + MAXB;                  // TOT
    unsigned short* Wb = (unsigned short*)(((uintptr_t)(col + TOT) + 255) & ~(uintptr_t)255);
    // Wb: 2 layers x (16384 hi + 16384 lo) ushorts = 128 KB

    const int gemmGrid = (N + 127) / 128;
    const int partGrid = (TOT + PCHUNK - 1) / PCHUNK;
    const int gatGrid  = (N + 7) / 8;

    // ---------------- weight repack + CSR build + graph bounds ----------
    repack_w<<<2, 256, 0, stream>>>(W1, W2, Wb);
    hipMemsetAsync(gcnt, 0, MAXB * 4, stream);
    bucket_hist<<<partGrid, 256, 0, stream>>>(ei, gcnt, E, TOT);
    bucket_scan<<<1, 256, 0, stream>>>(gcnt, bstart, gcursor, NB, TOT);
    partition_edges<<<partGrid, 256, 0, stream>>>(ei, gcursor, tmp, E, TOT);
    bucket_build<<<NB, 256, 0, stream>>>(tmp, bstart, rowptr, col, N, TOT, NB);
    graph_bounds<<<(N + 255) / 256, 256, 0, stream>>>(batch, gstart, N, G);

    // ---------------- layer 1 ----------------
    gemm_mfma_f32<<<gemmGrid, 256, 0, stream>>>(x, Wb, asrc1, adst1, hb, as_, ad_, N);
    gat_csr3<<<gatGrid, 256, 0, stream>>>(rowptr, col, (const uint2*)hb, as_, ad_, b1, (uint2*)h2b, N);

    // ---------------- layer 2 ----------------
    gemm_mfma_bf16<<<gemmGrid, 256, 0, stream>>>((const __bf16*)h2b, Wb + 32768, asrc2, adst2, hb, as_, ad_, N);
    gat_csr3<<<gatGrid, 256, 0, stream>>>(rowptr, col, (const uint2*)hb, as_, ad_, b2, (uint2*)h2b, N);

    // ---------------- pool + head ----------------
    pool_head<<<G, 128, 0, stream>>>(h2b, gstart, Wfc1, bfc1, Wfc2, bfc2, out);
}